// Round 11
// baseline (113.647 us; speedup 1.0000x reference)
//
#include <hip/hip_runtime.h>
#include <math.h>

#define TOTAL 2560
#define NEG_BIG (-1e30f)
#define LOG2E_8 0.18033688011112042f   // 0.125 * log2(e)

typedef __bf16 bf16x8 __attribute__((ext_vector_type(8)));
typedef float f32x4 __attribute__((ext_vector_type(4)));
typedef unsigned short ushort8v __attribute__((ext_vector_type(8)));
typedef unsigned short ushort4v __attribute__((ext_vector_type(4)));

__device__ inline unsigned short f2bf(float f) {
    unsigned u = __builtin_bit_cast(unsigned, f);
    u += 0x7fff + ((u >> 16) & 1);
    return (unsigned short)(u >> 16);
}

__device__ inline void gload16(const void* g, void* l) {
    __builtin_amdgcn_global_load_lds(
        (const __attribute__((address_space(1))) void*)g,
        (__attribute__((address_space(3))) void*)l, 16, 0, 0);
}

// ---------------- positional encoding (4 points / block) ----------------
__global__ __launch_bounds__(256) void pos_kernel(
    const float* __restrict__ coords,
    const float* __restrict__ pos_w,
    const float* __restrict__ pos_b,
    float* __restrict__ pos_out)
{
    __shared__ float enc[4][100];
    const int wv   = threadIdx.x >> 6;
    const int lane = threadIdx.x & 63;
    const int p = blockIdx.x * 4 + wv;
    const float c0 = coords[p * 3 + 0];
    const float c1 = coords[p * 3 + 1];
    const float c2 = coords[p * 3 + 2];
    for (int i = lane; i < 99; i += 64) {
        float v;
        if (i < 96) {
            const int d = i >> 5;
            const int j = i & 31;
            const float cv = (d == 0) ? c0 : ((d == 1) ? c1 : c2);
            const float freq = exp2f((float)(j & 15)) * 3.14159265358979323846f;
            const float sc = cv * freq;
            v = (j < 16) ? sinf(sc) : cosf(sc);
        } else {
            v = (i == 96) ? c0 : ((i == 97) ? c1 : c2);
        }
        enc[wv][i] = v;
    }
    float acc = pos_b[lane];
    const float* w = pos_w + lane * 99;
    for (int i = 0; i < 99; ++i) acc = fmaf(enc[wv][i], w[i], acc);
    pos_out[p * 64 + lane] = acc;
}

// ---------------- fp32 -> bf16 cast (features, qkv_w, proj_w) ----------------
__global__ __launch_bounds__(256) void cast_kernel(
    const float* __restrict__ f,  const float* __restrict__ qw, const float* __restrict__ pw,
    unsigned short* __restrict__ fb, unsigned short* __restrict__ qwb, unsigned short* __restrict__ pwb)
{
    const int s = blockIdx.x * 256 + threadIdx.x;
    const float* src; unsigned short* dst; int ls;
    if (s < 163840)      { src = f;  dst = fb;  ls = s; }
    else if (s < 262144) { src = qw; dst = qwb; ls = s - 163840; }
    else                 { src = pw; dst = pwb; ls = s - 262144; }
    const float4 x0 = *(const float4*)(src + ls * 8);
    const float4 x1 = *(const float4*)(src + ls * 8 + 4);
    ushort8v o;
    o[0] = f2bf(x0.x); o[1] = f2bf(x0.y); o[2] = f2bf(x0.z); o[3] = f2bf(x0.w);
    o[4] = f2bf(x1.x); o[5] = f2bf(x1.y); o[6] = f2bf(x1.z); o[7] = f2bf(x1.w);
    *(ushort8v*)(dst + ls * 8) = o;
}

// ---------------- QKV GEMM: bf16 MFMA, 64x64 tile, gload_lds dbuf (proven) ----
__global__ __launch_bounds__(256) void qkv_mfma_kernel(
    const unsigned short* __restrict__ A,
    const unsigned short* __restrict__ Bm,
    const float* __restrict__ pos,
    unsigned short* __restrict__ q_ws,
    unsigned short* __restrict__ k_ws,
    unsigned short* __restrict__ vt_ws)
{
    __shared__ unsigned short Abuf[2][64 * 64];
    __shared__ unsigned short Bbuf[2][64 * 64];
    const int m0 = blockIdx.x * 64;
    const int n0 = blockIdx.y * 64;
    const int t = threadIdx.x;
    const int w = t >> 6, lane = t & 63;
    const int wr = w >> 1, wc = w & 1;
    const int c = lane & 15, g = lane >> 4;

    auto STAGE = [&](int kt, int cur) {
#pragma unroll
        for (int i = 0; i < 2; ++i) {
            const int off = w * 2048 + i * 1024;
            const int ba  = off + lane * 16;
            const int row = ba >> 7;
            const int slot = (ba & 127) >> 4;
            gload16(A  + (m0 + row) * 512 + kt * 64 + ((slot ^ (row & 7)) * 8),
                    (char*)&Abuf[cur][0] + off);
            gload16(Bm + (n0 + row) * 512 + kt * 64 + ((slot ^ (row & 7)) * 8),
                    (char*)&Bbuf[cur][0] + off);
        }
    };

    f32x4 acc[2][2];
#pragma unroll
    for (int mi = 0; mi < 2; ++mi)
#pragma unroll
        for (int ni = 0; ni < 2; ++ni) acc[mi][ni] = (f32x4){0.f, 0.f, 0.f, 0.f};

    STAGE(0, 0);
    int cur = 0;
    for (int kt = 0; kt < 8; ++kt) {
        __syncthreads();
        if (kt + 1 < 8) STAGE(kt + 1, cur ^ 1);
#pragma unroll
        for (int kk = 0; kk < 2; ++kk) {
            bf16x8 af[2], bfr[2];
#pragma unroll
            for (int mi = 0; mi < 2; ++mi) {
                const int row = wr * 32 + mi * 16 + c;
                af[mi] = *(const bf16x8*)&Abuf[cur][row * 64 + ((g + 4 * kk) ^ (row & 7)) * 8];
            }
#pragma unroll
            for (int ni = 0; ni < 2; ++ni) {
                const int row = wc * 32 + ni * 16 + c;
                bfr[ni] = *(const bf16x8*)&Bbuf[cur][row * 64 + ((g + 4 * kk) ^ (row & 7)) * 8];
            }
#pragma unroll
            for (int mi = 0; mi < 2; ++mi)
#pragma unroll
                for (int ni = 0; ni < 2; ++ni)
                    acc[mi][ni] = __builtin_amdgcn_mfma_f32_16x16x32_bf16(af[mi], bfr[ni], acc[mi][ni], 0, 0, 0);
        }
        cur ^= 1;
    }

    const int which = n0 >> 9;
    const int h = (n0 >> 6) & 7;
#pragma unroll
    for (int mi = 0; mi < 2; ++mi)
#pragma unroll
        for (int ni = 0; ni < 2; ++ni) {
            const int dd = wc * 32 + ni * 16 + c;
            const int p0 = m0 + wr * 32 + mi * 16 + 4 * g;
            if (which == 2) {
                ushort4v o4;
#pragma unroll
                for (int r = 0; r < 4; ++r) o4[r] = f2bf(acc[mi][ni][r]);
                *(ushort4v*)(vt_ws + (h * 64 + dd) * TOTAL + p0) = o4;
            } else {
#pragma unroll
                for (int r = 0; r < 4; ++r) {
                    const int p = p0 + r;
                    const float v = acc[mi][ni][r] + pos[p * 64 + dd];
                    const int idx = (h * TOTAL + p) * 64 + dd;
                    if (which == 0) q_ws[idx] = f2bf(v);
                    else            k_ws[idx] = f2bf(v);
                }
            }
        }
}

// ---------------- flash attention pass 1: NO K/V LDS, split-K over keys -------
// grid 576: [0,64) batch0 (unsplit, FINAL rows into o_part[0]); [64,576) batch1,
// sp=(bx-64)>>8, f32 partials + (m,l) exp2-domain. K/V MFMA frags read DIRECTLY
// from global (L1/L2-resident); only P goes through (wave-local) LDS. No barriers.
__global__ __launch_bounds__(256) void attn_part_kernel(
    const unsigned short* __restrict__ q_ws,
    const unsigned short* __restrict__ k_ws,
    const unsigned short* __restrict__ vt_ws,
    float* __restrict__ o_part,          // [2][2560][512]
    float2* __restrict__ ml2)            // [2][2560][8]
{
    const int bx = blockIdx.x;
    int b, qt, h, sp, t0, t1;
    if (bx < 64) {
        b = 0; h = bx >> 3; qt = bx & 7; sp = 0; t0 = 0; t1 = 4;
    } else {
        b = 1;
        const int idx = bx - 64;
        sp = idx >> 8;
        const int rr = idx & 255;
        h = rr >> 5; qt = rr & 31;
        const int kt0 = (qt < 8) ? 4 : 0;      // mask: skip k<512 for q<512
        const int mid = (kt0 + 16) >> 1;
        t0 = sp ? mid : kt0;
        t1 = sp ? 16 : mid;
    }
    const int base = b ? 512 : 0;

    const int t    = threadIdx.x;
    const int w    = t >> 6;
    const int lane = t & 63;
    const int g    = lane >> 4;
    const int c    = lane & 15;

    __shared__ unsigned short P_lds[64][72];       // [q][k-half], wave-local rows

    const unsigned short* Qrow = q_ws + ((h * TOTAL) + base + qt * 64 + 16 * w + c) * 64;
    const bf16x8 qa0 = *(const bf16x8*)(Qrow + 8 * g);
    const bf16x8 qa1 = *(const bf16x8*)(Qrow + 8 * g + 32);

    float m_old = NEG_BIG, l_old = 0.f;     // state for q = 16w + c (lane-local)
    f32x4 o_acc[4];
#pragma unroll
    for (int n = 0; n < 4; ++n) o_acc[n] = (f32x4){0.f, 0.f, 0.f, 0.f};

    const unsigned short* Kg = k_ws + (h * TOTAL + base) * 64;
    const unsigned short* Vg = vt_ws + h * 64 * TOTAL + base;

    for (int kt = t0; kt < t1; ++kt) {
        const unsigned short* Kt = Kg + kt * 128 * 64;   // [key][d] tile
        const unsigned short* Vt = Vg + kt * 128;        // [d][key] tile (stride TOTAL)

        // S^T via swapped operands: s_acc[n][r] = S[q=16w+c][k=16n+4g+r]
        f32x4 s_acc[8];
#pragma unroll
        for (int n = 0; n < 8; ++n) {
            f32x4 acc = (f32x4){0.f, 0.f, 0.f, 0.f};
            const bf16x8 kb0 = *(const bf16x8*)(Kt + (16 * n + c) * 64 + 8 * g);
            const bf16x8 kb1 = *(const bf16x8*)(Kt + (16 * n + c) * 64 + 8 * g + 32);
            acc = __builtin_amdgcn_mfma_f32_16x16x32_bf16(kb0, qa0, acc, 0, 0, 0);
            acc = __builtin_amdgcn_mfma_f32_16x16x32_bf16(kb1, qa1, acc, 0, 0, 0);
            s_acc[n] = acc;
        }

        // lane-local softmax over the 32 in-register values + 2 lane-hop reduces
        float mx01, mx23;
        {
            f32x4 m4 = s_acc[0];
#pragma unroll
            for (int n = 1; n < 8; ++n) {
#pragma unroll
                for (int r = 0; r < 4; ++r) m4[r] = fmaxf(m4[r], s_acc[n][r]);
            }
            mx01 = fmaxf(m4[0], m4[1]); mx23 = fmaxf(m4[2], m4[3]);
        }
        float tm = fmaxf(mx01, mx23) * LOG2E_8;
        tm = fmaxf(tm, __shfl_xor(tm, 16));
        tm = fmaxf(tm, __shfl_xor(tm, 32));
        const float m_new = fmaxf(m_old, tm);
        const float corr = exp2f(m_old - m_new);
        float rs = 0.f;
#pragma unroll
        for (int n = 0; n < 8; ++n)
#pragma unroll
            for (int r = 0; r < 4; ++r) {
                const float pv = exp2f(fmaf(s_acc[n][r], LOG2E_8, -m_new));
                s_acc[n][r] = pv;
                rs += pv;
            }
        rs += __shfl_xor(rs, 16);
        rs += __shfl_xor(rs, 32);
        l_old = l_old * corr + rs;
        m_old = m_new;

        // rescale o_acc rows (q = 16w+4g+r): fetch corr from owner lanes
        float corr_r[4];
#pragma unroll
        for (int r = 0; r < 4; ++r) corr_r[r] = __shfl(corr, 4 * g + r);
#pragma unroll
        for (int n = 0; n < 4; ++n)
#pragma unroll
            for (int r = 0; r < 4; ++r) o_acc[n][r] *= corr_r[r];

        // PV in two 64-key halves; P via wave-local LDS, V frags direct-global
#pragma unroll
        for (int half = 0; half < 2; ++half) {
#pragma unroll
            for (int n = 0; n < 4; ++n) {
                ushort4v pk;
#pragma unroll
                for (int r = 0; r < 4; ++r) pk[r] = f2bf(s_acc[half * 4 + n][r]);
                *(ushort4v*)&P_lds[16 * w + c][16 * n + 4 * g] = pk;
            }
#pragma unroll
            for (int kk = 0; kk < 2; ++kk) {
                const bf16x8 pa = *(const bf16x8*)&P_lds[16 * w + c][8 * g + 32 * kk];
                const int koff = 8 * g + 32 * (half * 2 + kk);
#pragma unroll
                for (int n = 0; n < 4; ++n) {
                    const bf16x8 vb = *(const bf16x8*)(Vt + (16 * n + c) * TOTAL + koff);
                    o_acc[n] = __builtin_amdgcn_mfma_f32_16x16x32_bf16(pa, vb, o_acc[n], 0, 0, 0);
                }
            }
        }
    }

    if (b == 0) {
        // finalize batch0: analytic 1536 zero-keys + normalize (final output rows)
        const float mn  = fmaxf(m_old, 0.f);
        const float ccf = exp2f(m_old - mn);
        const float l   = l_old * ccf + 1536.0f * exp2f(-mn);
        const float inv_own = ccf / l;
        float inv_r[4];
#pragma unroll
        for (int r = 0; r < 4; ++r) inv_r[r] = __shfl(inv_own, 4 * g + r);
        float* op = o_part + (size_t)(qt * 64 + 16 * w) * 512 + h * 64;
#pragma unroll
        for (int n = 0; n < 4; ++n)
#pragma unroll
            for (int r = 0; r < 4; ++r)
                op[(4 * g + r) * 512 + 16 * n + c] = o_acc[n][r] * inv_r[r];
    } else {
        float* op = o_part + (size_t)sp * (TOTAL * 512)
                  + (size_t)(512 + qt * 64 + 16 * w) * 512 + h * 64;
#pragma unroll
        for (int n = 0; n < 4; ++n)
#pragma unroll
            for (int r = 0; r < 4; ++r)
                op[(4 * g + r) * 512 + 16 * n + c] = o_acc[n][r];
        if (lane < 16) {   // g==0 lanes own rows q=16w+c with full (m,l)
            const int p = 512 + qt * 64 + 16 * w + c;
            ml2[(sp * TOTAL + p) * 8 + h] = make_float2(m_old, l_old);
        }
    }
}

// ---------------- split combine: y_bf = normalize(o0, o1) (round-8 proven) ----
__global__ __launch_bounds__(256) void combine_kernel(
    const float* __restrict__ o_part,    // [2][2560][512]
    const float2* __restrict__ ml2,      // [2][2560][8]
    unsigned short* __restrict__ y)
{
    const int e = blockIdx.x * 256 + threadIdx.x;   // < 163840
    const int p = e >> 6;
    const int seg = e & 63;
    const size_t bo = (size_t)p * 512 + seg * 8;
    const float4 a0 = *(const float4*)(o_part + bo);
    const float4 a1 = *(const float4*)(o_part + bo + 4);
    ushort8v y8;
    if (p < 512) {
        y8[0] = f2bf(a0.x); y8[1] = f2bf(a0.y); y8[2] = f2bf(a0.z); y8[3] = f2bf(a0.w);
        y8[4] = f2bf(a1.x); y8[5] = f2bf(a1.y); y8[6] = f2bf(a1.z); y8[7] = f2bf(a1.w);
    } else {
        const int h = seg >> 3;
        const float2 v0 = ml2[(size_t)p * 8 + h];
        const float2 v1 = ml2[(size_t)(TOTAL + p) * 8 + h];
        const float mt = fmaxf(v0.x, v1.x);
        const float c0 = exp2f(v0.x - mt), c1 = exp2f(v1.x - mt);
        const float inv = 1.0f / fmaf(v0.y, c0, v1.y * c1);
        const float f0 = c0 * inv, f1 = c1 * inv;
        const float4 b0 = *(const float4*)(o_part + (size_t)TOTAL * 512 + bo);
        const float4 b1 = *(const float4*)(o_part + (size_t)TOTAL * 512 + bo + 4);
        y8[0] = f2bf(fmaf(a0.x, f0, b0.x * f1));
        y8[1] = f2bf(fmaf(a0.y, f0, b0.y * f1));
        y8[2] = f2bf(fmaf(a0.z, f0, b0.z * f1));
        y8[3] = f2bf(fmaf(a0.w, f0, b0.w * f1));
        y8[4] = f2bf(fmaf(a1.x, f0, b1.x * f1));
        y8[5] = f2bf(fmaf(a1.y, f0, b1.y * f1));
        y8[6] = f2bf(fmaf(a1.z, f0, b1.z * f1));
        y8[7] = f2bf(fmaf(a1.w, f0, b1.w * f1));
    }
    *(ushort8v*)(y + bo) = y8;
}

// ---------------- output projection: bf16 MFMA, 64x64 tile (proven) -----------
__global__ __launch_bounds__(256) void proj_mfma_kernel(
    const unsigned short* __restrict__ A,    // y_bf [2560][512]
    const unsigned short* __restrict__ Bm,   // projw_bf [512][512]
    const float* __restrict__ bias,
    float* __restrict__ out)
{
    __shared__ unsigned short Abuf[2][64 * 64];
    __shared__ unsigned short Bbuf[2][64 * 64];
    const int m0 = blockIdx.x * 64;
    const int n0 = blockIdx.y * 64;
    const int t = threadIdx.x;
    const int w = t >> 6, lane = t & 63;
    const int wr = w >> 1, wc = w & 1;
    const int c = lane & 15, g = lane >> 4;

    auto STAGE = [&](int kt, int cur) {
#pragma unroll
        for (int i = 0; i < 2; ++i) {
            const int off = w * 2048 + i * 1024;
            const int ba  = off + lane * 16;
            const int row = ba >> 7;
            const int slot = (ba & 127) >> 4;
            gload16(A  + (m0 + row) * 512 + kt * 64 + ((slot ^ (row & 7)) * 8),
                    (char*)&Abuf[cur][0] + off);
            gload16(Bm + (n0 + row) * 512 + kt * 64 + ((slot ^ (row & 7)) * 8),
                    (char*)&Bbuf[cur][0] + off);
        }
    };

    f32x4 acc[2][2];
#pragma unroll
    for (int mi = 0; mi < 2; ++mi)
#pragma unroll
        for (int ni = 0; ni < 2; ++ni) acc[mi][ni] = (f32x4){0.f, 0.f, 0.f, 0.f};

    STAGE(0, 0);
    int cur = 0;
    for (int kt = 0; kt < 8; ++kt) {
        __syncthreads();
        if (kt + 1 < 8) STAGE(kt + 1, cur ^ 1);
#pragma unroll
        for (int kk = 0; kk < 2; ++kk) {
            bf16x8 af[2], bfr[2];
#pragma unroll
            for (int mi = 0; mi < 2; ++mi) {
                const int row = wr * 32 + mi * 16 + c;
                af[mi] = *(const bf16x8*)&Abuf[cur][row * 64 + ((g + 4 * kk) ^ (row & 7)) * 8];
            }
#pragma unroll
            for (int ni = 0; ni < 2; ++ni) {
                const int row = wc * 32 + ni * 16 + c;
                bfr[ni] = *(const bf16x8*)&Bbuf[cur][row * 64 + ((g + 4 * kk) ^ (row & 7)) * 8];
            }
#pragma unroll
            for (int mi = 0; mi < 2; ++mi)
#pragma unroll
                for (int ni = 0; ni < 2; ++ni)
                    acc[mi][ni] = __builtin_amdgcn_mfma_f32_16x16x32_bf16(af[mi], bfr[ni], acc[mi][ni], 0, 0, 0);
        }
        cur ^= 1;
    }

#pragma unroll
    for (int mi = 0; mi < 2; ++mi)
#pragma unroll
        for (int ni = 0; ni < 2; ++ni) {
            const int col = n0 + wc * 32 + ni * 16 + c;
            const float bv = bias[col];
#pragma unroll
            for (int r = 0; r < 4; ++r) {
                const int p = m0 + wr * 32 + mi * 16 + 4 * g + r;
                out[p * 512 + col] = acc[mi][ni][r] + bv;
            }
        }
}

extern "C" void kernel_launch(void* const* d_in, const int* in_sizes, int n_in,
                              void* d_out, int out_size, void* d_ws, size_t ws_size,
                              hipStream_t stream) {
    const float* features = (const float*)d_in[0];
    const float* coords   = (const float*)d_in[1];
    const float* qkv_w    = (const float*)d_in[2];
    const float* proj_w   = (const float*)d_in[3];
    const float* proj_b   = (const float*)d_in[4];
    const float* pos_w    = (const float*)d_in[5];
    const float* pos_b    = (const float*)d_in[6];
    float* out = (float*)d_out;

    float* pos_ws = (float*)d_ws;                                    // 163840 f32
    unsigned short* feat_bf  = (unsigned short*)(pos_ws + TOTAL * 64);
    unsigned short* qkvw_bf  = feat_bf + 2560 * 512;
    unsigned short* projw_bf = qkvw_bf + 1536 * 512;
    unsigned short* q_ws  = projw_bf + 512 * 512;
    unsigned short* k_ws  = q_ws  + 8 * TOTAL * 64;
    unsigned short* vt_ws = k_ws  + 8 * TOTAL * 64;
    float* o_part = (float*)(vt_ws + 8 * TOTAL * 64);                // 2 * 2560*512 f32
    float2* ml2   = (float2*)(o_part + 2 * TOTAL * 512);             // 2 * 2560*8 float2
    unsigned short* y_bf = (unsigned short*)(ml2 + 2 * TOTAL * 8);   // 2560*512 bf16

    pos_kernel<<<dim3(TOTAL / 4), dim3(256), 0, stream>>>(coords, pos_w, pos_b, pos_ws);
    cast_kernel<<<dim3(1152), dim3(256), 0, stream>>>(
        features, qkv_w, proj_w, feat_bf, qkvw_bf, projw_bf);
    qkv_mfma_kernel<<<dim3(40, 24), dim3(256), 0, stream>>>(
        feat_bf, qkvw_bf, pos_ws, q_ws, k_ws, vt_ws);
    attn_part_kernel<<<dim3(576), dim3(256), 0, stream>>>(
        q_ws, k_ws, vt_ws, o_part, ml2);
    combine_kernel<<<dim3(640), dim3(256), 0, stream>>>(o_part, ml2, y_bf);
    proj_mfma_kernel<<<dim3(40, 8), dim3(256), 0, stream>>>(
        y_bf, projw_bf, proj_b, out);
}

// Round 12
// 80.259 us; speedup vs baseline: 1.4160x; 1.4160x over previous
//
#include <hip/hip_runtime.h>
#include <math.h>

#define TOTAL 2560
#define NEG_BIG (-1e30f)
#define LOG2E_8 0.18033688011112042f   // 0.125 * log2(e)

typedef __bf16 bf16x8 __attribute__((ext_vector_type(8)));
typedef float f32x4 __attribute__((ext_vector_type(4)));
typedef unsigned short ushort8v __attribute__((ext_vector_type(8)));
typedef unsigned short ushort4v __attribute__((ext_vector_type(4)));

__device__ inline unsigned short f2bf(float f) {
    unsigned u = __builtin_bit_cast(unsigned, f);
    u += 0x7fff + ((u >> 16) & 1);
    return (unsigned short)(u >> 16);
}

__device__ inline void gload16(const void* g, void* l) {
    __builtin_amdgcn_global_load_lds(
        (const __attribute__((address_space(1))) void*)g,
        (__attribute__((address_space(3))) void*)l, 16, 0, 0);
}

// ---------------- positional encoding (4 points / block) ----------------
__global__ __launch_bounds__(256) void pos_kernel(
    const float* __restrict__ coords,
    const float* __restrict__ pos_w,
    const float* __restrict__ pos_b,
    float* __restrict__ pos_out)
{
    __shared__ float enc[4][100];
    const int wv   = threadIdx.x >> 6;
    const int lane = threadIdx.x & 63;
    const int p = blockIdx.x * 4 + wv;
    const float c0 = coords[p * 3 + 0];
    const float c1 = coords[p * 3 + 1];
    const float c2 = coords[p * 3 + 2];
    for (int i = lane; i < 99; i += 64) {
        float v;
        if (i < 96) {
            const int d = i >> 5;
            const int j = i & 31;
            const float cv = (d == 0) ? c0 : ((d == 1) ? c1 : c2);
            const float freq = exp2f((float)(j & 15)) * 3.14159265358979323846f;
            const float sc = cv * freq;
            v = (j < 16) ? sinf(sc) : cosf(sc);
        } else {
            v = (i == 96) ? c0 : ((i == 97) ? c1 : c2);
        }
        enc[wv][i] = v;
    }
    float acc = pos_b[lane];
    const float* w = pos_w + lane * 99;
    for (int i = 0; i < 99; ++i) acc = fmaf(enc[wv][i], w[i], acc);
    pos_out[p * 64 + lane] = acc;
}

// ---------------- fp32 -> bf16 cast (features, qkv_w, proj_w) ----------------
__global__ __launch_bounds__(256) void cast_kernel(
    const float* __restrict__ f,  const float* __restrict__ qw, const float* __restrict__ pw,
    unsigned short* __restrict__ fb, unsigned short* __restrict__ qwb, unsigned short* __restrict__ pwb)
{
    const int s = blockIdx.x * 256 + threadIdx.x;
    const float* src; unsigned short* dst; int ls;
    if (s < 163840)      { src = f;  dst = fb;  ls = s; }
    else if (s < 262144) { src = qw; dst = qwb; ls = s - 163840; }
    else                 { src = pw; dst = pwb; ls = s - 262144; }
    const float4 x0 = *(const float4*)(src + ls * 8);
    const float4 x1 = *(const float4*)(src + ls * 8 + 4);
    ushort8v o;
    o[0] = f2bf(x0.x); o[1] = f2bf(x0.y); o[2] = f2bf(x0.z); o[3] = f2bf(x0.w);
    o[4] = f2bf(x1.x); o[5] = f2bf(x1.y); o[6] = f2bf(x1.z); o[7] = f2bf(x1.w);
    *(ushort8v*)(dst + ls * 8) = o;
}

// ---------------- QKV GEMM: bf16 MFMA, 64x64 tile, gload_lds dbuf (proven) ----
__global__ __launch_bounds__(256) void qkv_mfma_kernel(
    const unsigned short* __restrict__ A,
    const unsigned short* __restrict__ Bm,
    const float* __restrict__ pos,
    unsigned short* __restrict__ q_ws,
    unsigned short* __restrict__ k_ws,
    unsigned short* __restrict__ vt_ws)
{
    __shared__ unsigned short Abuf[2][64 * 64];
    __shared__ unsigned short Bbuf[2][64 * 64];
    const int m0 = blockIdx.x * 64;
    const int n0 = blockIdx.y * 64;
    const int t = threadIdx.x;
    const int w = t >> 6, lane = t & 63;
    const int wr = w >> 1, wc = w & 1;
    const int c = lane & 15, g = lane >> 4;

    auto STAGE = [&](int kt, int cur) {
#pragma unroll
        for (int i = 0; i < 2; ++i) {
            const int off = w * 2048 + i * 1024;
            const int ba  = off + lane * 16;
            const int row = ba >> 7;
            const int slot = (ba & 127) >> 4;
            gload16(A  + (m0 + row) * 512 + kt * 64 + ((slot ^ (row & 7)) * 8),
                    (char*)&Abuf[cur][0] + off);
            gload16(Bm + (n0 + row) * 512 + kt * 64 + ((slot ^ (row & 7)) * 8),
                    (char*)&Bbuf[cur][0] + off);
        }
    };

    f32x4 acc[2][2];
#pragma unroll
    for (int mi = 0; mi < 2; ++mi)
#pragma unroll
        for (int ni = 0; ni < 2; ++ni) acc[mi][ni] = (f32x4){0.f, 0.f, 0.f, 0.f};

    STAGE(0, 0);
    int cur = 0;
    for (int kt = 0; kt < 8; ++kt) {
        __syncthreads();
        if (kt + 1 < 8) STAGE(kt + 1, cur ^ 1);
#pragma unroll
        for (int kk = 0; kk < 2; ++kk) {
            bf16x8 af[2], bfr[2];
#pragma unroll
            for (int mi = 0; mi < 2; ++mi) {
                const int row = wr * 32 + mi * 16 + c;
                af[mi] = *(const bf16x8*)&Abuf[cur][row * 64 + ((g + 4 * kk) ^ (row & 7)) * 8];
            }
#pragma unroll
            for (int ni = 0; ni < 2; ++ni) {
                const int row = wc * 32 + ni * 16 + c;
                bfr[ni] = *(const bf16x8*)&Bbuf[cur][row * 64 + ((g + 4 * kk) ^ (row & 7)) * 8];
            }
#pragma unroll
            for (int mi = 0; mi < 2; ++mi)
#pragma unroll
                for (int ni = 0; ni < 2; ++ni)
                    acc[mi][ni] = __builtin_amdgcn_mfma_f32_16x16x32_bf16(af[mi], bfr[ni], acc[mi][ni], 0, 0, 0);
        }
        cur ^= 1;
    }

    const int which = n0 >> 9;
    const int h = (n0 >> 6) & 7;
#pragma unroll
    for (int mi = 0; mi < 2; ++mi)
#pragma unroll
        for (int ni = 0; ni < 2; ++ni) {
            const int dd = wc * 32 + ni * 16 + c;
            const int p0 = m0 + wr * 32 + mi * 16 + 4 * g;
            if (which == 2) {
                ushort4v o4;
#pragma unroll
                for (int r = 0; r < 4; ++r) o4[r] = f2bf(acc[mi][ni][r]);
                *(ushort4v*)(vt_ws + (h * 64 + dd) * TOTAL + p0) = o4;
            } else {
#pragma unroll
                for (int r = 0; r < 4; ++r) {
                    const int p = p0 + r;
                    const float v = acc[mi][ni][r] + pos[p * 64 + dd];
                    const int idx = (h * TOTAL + p) * 64 + dd;
                    if (which == 0) q_ws[idx] = f2bf(v);
                    else            k_ws[idx] = f2bf(v);
                }
            }
        }
}

// ---------------- flash attention pass 1: 2 Q-frags/wave, KVBLK=64, split-K ---
// grid 288: [0,32) batch0 (128q blocks, unsplit, FINAL rows); [32,288) batch1,
// sp=(bx-32)>>7. 4 waves, wave w owns q rows 32w..32w+31 (lo: +c, hi: +16+c).
// K/V LDS dbuf via gload16 (pre-swizzled source); P via XOR-slotted [128][64].
__global__ __launch_bounds__(256) void attn_part_kernel(
    const unsigned short* __restrict__ q_ws,
    const unsigned short* __restrict__ k_ws,
    const unsigned short* __restrict__ vt_ws,
    float* __restrict__ o_part,          // [2][2560][512]
    float2* __restrict__ ml2)            // [2][2560][8]
{
    const int bx = blockIdx.x;
    int b, qt, h, sp, t0, t1;
    if (bx < 32) {
        b = 0; h = bx >> 2; qt = bx & 3; sp = 0; t0 = 0; t1 = 8;
    } else {
        b = 1;
        const int idx = bx - 32;
        sp = idx >> 7;
        const int rr0 = idx & 127;
        h = rr0 >> 4; qt = rr0 & 15;
        const int kt0 = (qt < 4) ? 8 : 0;     // mask: skip keys<512 for q<512
        const int mid = (kt0 + 32) >> 1;
        t0 = sp ? mid : kt0;
        t1 = sp ? 32 : mid;
    }
    const int base = b ? 512 : 0;

    const int t    = threadIdx.x;
    const int w    = t >> 6;
    const int lane = t & 63;
    const int g    = lane >> 4;
    const int c    = lane & 15;
    const int c7   = c & 7;

    __shared__ unsigned short Kbuf[2][64 * 64];   // [key][d], XOR-slotted
    __shared__ unsigned short Vbuf[2][64 * 64];   // [d][key], XOR-slotted
    __shared__ unsigned short P_lds[128 * 64];    // [q][key], XOR-slotted, wave-local rows

    const unsigned short* Qrow = q_ws + ((h * TOTAL) + base + qt * 128 + 32 * w + c) * 64;
    const bf16x8 qlo0 = *(const bf16x8*)(Qrow + 8 * g);
    const bf16x8 qlo1 = *(const bf16x8*)(Qrow + 8 * g + 32);
    const bf16x8 qhi0 = *(const bf16x8*)(Qrow + 16 * 64 + 8 * g);
    const bf16x8 qhi1 = *(const bf16x8*)(Qrow + 16 * 64 + 8 * g + 32);

    float m_lo = NEG_BIG, l_lo = 0.f, m_hi = NEG_BIG, l_hi = 0.f;
    f32x4 o_lo[4], o_hi[4];
#pragma unroll
    for (int n = 0; n < 4; ++n) {
        o_lo[n] = (f32x4){0.f, 0.f, 0.f, 0.f};
        o_hi[n] = (f32x4){0.f, 0.f, 0.f, 0.f};
    }

    const unsigned short* Kg = k_ws + (h * TOTAL + base) * 64;
    const unsigned short* Vg = vt_ws + h * 64 * TOTAL + base;

    // stage one 64-key tile (K 8KB + V 8KB); 2 gload16 pairs per thread
    auto STAGE = [&](int kt, int cur) {
#pragma unroll
        for (int i = 0; i < 2; ++i) {
            const int off = w * 2048 + i * 1024;
            const int ba  = off + lane * 16;
            const int row = ba >> 7;              // 0..63
            const int slot = (ba & 127) >> 4;     // 0..7
            gload16(Kg + (kt * 64 + row) * 64 + ((slot ^ (row & 7)) * 8),
                    (char*)&Kbuf[cur][0] + off);
            gload16(Vg + row * TOTAL + kt * 64 + ((slot ^ (row & 7)) * 8),
                    (char*)&Vbuf[cur][0] + off);
        }
    };

    const int prow_lo = 32 * w + c;
    const int prow_hi = 32 * w + 16 + c;

    STAGE(t0, 0);
    int cur = 0;
    for (int kt = t0; kt < t1; ++kt) {
        __syncthreads();   // buf[cur] loads drained; prior tile's LDS reads done
        if (kt + 1 < t1) STAGE(kt + 1, cur ^ 1);

        const unsigned short* Ksh = &Kbuf[cur][0];
        const unsigned short* Vsh = &Vbuf[cur][0];

        float corr_lo, corr_hi;
#pragma unroll
        for (int half = 0; half < 2; ++half) {
            const bf16x8 qa0 = half ? qhi0 : qlo0;
            const bf16x8 qa1 = half ? qhi1 : qlo1;
            // S^T: s[n][r] = S[k = 16n+4g+r][q-row = (half? hi : lo)]
            f32x4 s[4];
#pragma unroll
            for (int n = 0; n < 4; ++n) {
                const int row = 16 * n + c;
                const bf16x8 kb0 = *(const bf16x8*)&Ksh[row * 64 + ((g + 0) ^ c7) * 8];
                const bf16x8 kb1 = *(const bf16x8*)&Ksh[row * 64 + ((g + 4) ^ c7) * 8];
                f32x4 a = __builtin_amdgcn_mfma_f32_16x16x32_bf16(kb0, qa0, (f32x4){0.f,0.f,0.f,0.f}, 0, 0, 0);
                s[n] = __builtin_amdgcn_mfma_f32_16x16x32_bf16(kb1, qa1, a, 0, 0, 0);
            }
            // lane-local softmax over 16 regs + 2 lane-hop reduce (g-dim)
            float m_old = half ? m_hi : m_lo;
            float l_old = half ? l_hi : l_lo;
            f32x4 m4 = s[0];
#pragma unroll
            for (int n = 1; n < 4; ++n)
#pragma unroll
                for (int r = 0; r < 4; ++r) m4[r] = fmaxf(m4[r], s[n][r]);
            float tm = fmaxf(fmaxf(m4[0], m4[1]), fmaxf(m4[2], m4[3])) * LOG2E_8;
            tm = fmaxf(tm, __shfl_xor(tm, 16));
            tm = fmaxf(tm, __shfl_xor(tm, 32));
            const float m_new = fmaxf(m_old, tm);
            const float corr = exp2f(m_old - m_new);
            float rs = 0.f;
#pragma unroll
            for (int n = 0; n < 4; ++n)
#pragma unroll
                for (int r = 0; r < 4; ++r) {
                    const float pv = exp2f(fmaf(s[n][r], LOG2E_8, -m_new));
                    s[n][r] = pv;
                    rs += pv;
                }
            rs += __shfl_xor(rs, 16);
            rs += __shfl_xor(rs, 32);
            l_old = l_old * corr + rs;
            if (half) { m_hi = m_new; l_hi = l_old; corr_hi = corr; }
            else      { m_lo = m_new; l_lo = l_old; corr_lo = corr; }
            // P write: keys 16n+4g+{0..3} -> 8B group (2n+(g>>1), g&1), slot-XOR'd
            const int prow = half ? prow_hi : prow_lo;
#pragma unroll
            for (int n = 0; n < 4; ++n) {
                ushort4v pk;
#pragma unroll
                for (int r = 0; r < 4; ++r) pk[r] = f2bf(s[n][r]);
                *(ushort4v*)&P_lds[prow * 64 + (((2 * n + (g >> 1)) ^ c7) * 8) + (g & 1) * 4] = pk;
            }
        }

        // rescale O (rows 4g+r): corr from owner lanes (g=0, c=4g+r)
        float clr[4], chr_[4];
#pragma unroll
        for (int r = 0; r < 4; ++r) {
            clr[r]  = __shfl(corr_lo, 4 * g + r);
            chr_[r] = __shfl(corr_hi, 4 * g + r);
        }
#pragma unroll
        for (int n = 0; n < 4; ++n)
#pragma unroll
            for (int r = 0; r < 4; ++r) { o_lo[n][r] *= clr[r]; o_hi[n][r] *= chr_[r]; }

        // PV: each vb serves both halves
#pragma unroll
        for (int kk = 0; kk < 2; ++kk) {
            const bf16x8 pa_lo = *(const bf16x8*)&P_lds[prow_lo * 64 + ((4 * kk + g) ^ c7) * 8];
            const bf16x8 pa_hi = *(const bf16x8*)&P_lds[prow_hi * 64 + ((4 * kk + g) ^ c7) * 8];
#pragma unroll
            for (int n = 0; n < 4; ++n) {
                const bf16x8 vb = *(const bf16x8*)&Vsh[(16 * n + c) * 64 + ((g + 4 * kk) ^ c7) * 8];
                o_lo[n] = __builtin_amdgcn_mfma_f32_16x16x32_bf16(pa_lo, vb, o_lo[n], 0, 0, 0);
                o_hi[n] = __builtin_amdgcn_mfma_f32_16x16x32_bf16(pa_hi, vb, o_hi[n], 0, 0, 0);
            }
        }
        cur ^= 1;
    }

    if (b == 0) {
        // finalize batch0: analytic 1536 zero-keys + normalize (final rows)
        const float mn_l = fmaxf(m_lo, 0.f);
        const float cl   = exp2f(m_lo - mn_l);
        const float il   = cl / (l_lo * cl + 1536.0f * exp2f(-mn_l));
        const float mn_h = fmaxf(m_hi, 0.f);
        const float ch   = exp2f(m_hi - mn_h);
        const float ih   = ch / (l_hi * ch + 1536.0f * exp2f(-mn_h));
        float ilr[4], ihr[4];
#pragma unroll
        for (int r = 0; r < 4; ++r) {
            ilr[r] = __shfl(il, 4 * g + r);
            ihr[r] = __shfl(ih, 4 * g + r);
        }
        float* op = o_part + (size_t)(qt * 128 + 32 * w) * 512 + h * 64;
#pragma unroll
        for (int n = 0; n < 4; ++n)
#pragma unroll
            for (int r = 0; r < 4; ++r) {
                op[(4 * g + r) * 512 + 16 * n + c]        = o_lo[n][r] * ilr[r];
                op[(16 + 4 * g + r) * 512 + 16 * n + c]   = o_hi[n][r] * ihr[r];
            }
    } else {
        float* op = o_part + (size_t)sp * (TOTAL * 512)
                  + (size_t)(512 + qt * 128 + 32 * w) * 512 + h * 64;
#pragma unroll
        for (int n = 0; n < 4; ++n)
#pragma unroll
            for (int r = 0; r < 4; ++r) {
                op[(4 * g + r) * 512 + 16 * n + c]      = o_lo[n][r];
                op[(16 + 4 * g + r) * 512 + 16 * n + c] = o_hi[n][r];
            }
        if (lane < 16) {   // g==0 lanes hold full (m,l) for their rows
            const int p = 512 + qt * 128 + 32 * w + c;
            ml2[((size_t)sp * TOTAL + p) * 8 + h]      = make_float2(m_lo, l_lo);
            ml2[((size_t)sp * TOTAL + p + 16) * 8 + h] = make_float2(m_hi, l_hi);
        }
    }
}

// ---------------- split combine: y_bf = normalize(o0, o1) (proven) -----------
__global__ __launch_bounds__(256) void combine_kernel(
    const float* __restrict__ o_part,    // [2][2560][512]
    const float2* __restrict__ ml2,      // [2][2560][8]
    unsigned short* __restrict__ y)
{
    const int e = blockIdx.x * 256 + threadIdx.x;   // < 163840
    const int p = e >> 6;
    const int seg = e & 63;
    const size_t bo = (size_t)p * 512 + seg * 8;
    const float4 a0 = *(const float4*)(o_part + bo);
    const float4 a1 = *(const float4*)(o_part + bo + 4);
    ushort8v y8;
    if (p < 512) {
        y8[0] = f2bf(a0.x); y8[1] = f2bf(a0.y); y8[2] = f2bf(a0.z); y8[3] = f2bf(a0.w);
        y8[4] = f2bf(a1.x); y8[5] = f2bf(a1.y); y8[6] = f2bf(a1.z); y8[7] = f2bf(a1.w);
    } else {
        const int h = seg >> 3;
        const float2 v0 = ml2[(size_t)p * 8 + h];
        const float2 v1 = ml2[(size_t)(TOTAL + p) * 8 + h];
        const float mt = fmaxf(v0.x, v1.x);
        const float c0 = exp2f(v0.x - mt), c1 = exp2f(v1.x - mt);
        const float inv = 1.0f / fmaf(v0.y, c0, v1.y * c1);
        const float f0 = c0 * inv, f1 = c1 * inv;
        const float4 b0 = *(const float4*)(o_part + (size_t)TOTAL * 512 + bo);
        const float4 b1 = *(const float4*)(o_part + (size_t)TOTAL * 512 + bo + 4);
        y8[0] = f2bf(fmaf(a0.x, f0, b0.x * f1));
        y8[1] = f2bf(fmaf(a0.y, f0, b0.y * f1));
        y8[2] = f2bf(fmaf(a0.z, f0, b0.z * f1));
        y8[3] = f2bf(fmaf(a0.w, f0, b0.w * f1));
        y8[4] = f2bf(fmaf(a1.x, f0, b1.x * f1));
        y8[5] = f2bf(fmaf(a1.y, f0, b1.y * f1));
        y8[6] = f2bf(fmaf(a1.z, f0, b1.z * f1));
        y8[7] = f2bf(fmaf(a1.w, f0, b1.w * f1));
    }
    *(ushort8v*)(y + bo) = y8;
}

// ---------------- output projection: bf16 MFMA, 64x64 tile (proven) -----------
__global__ __launch_bounds__(256) void proj_mfma_kernel(
    const unsigned short* __restrict__ A,    // y_bf [2560][512]
    const unsigned short* __restrict__ Bm,   // projw_bf [512][512]
    const float* __restrict__ bias,
    float* __restrict__ out)
{
    __shared__ unsigned short Abuf[2][64 * 64];
    __shared__ unsigned short Bbuf[2][64 * 64];
    const int m0 = blockIdx.x * 64;
    const int n0 = blockIdx.y * 64;
    const int t = threadIdx.x;
    const int w = t >> 6, lane = t & 63;
    const int wr = w >> 1, wc = w & 1;
    const int c = lane & 15, g = lane >> 4;

    auto STAGE = [&](int kt, int cur) {
#pragma unroll
        for (int i = 0; i < 2; ++i) {
            const int off = w * 2048 + i * 1024;
            const int ba  = off + lane * 16;
            const int row = ba >> 7;
            const int slot = (ba & 127) >> 4;
            gload16(A  + (m0 + row) * 512 + kt * 64 + ((slot ^ (row & 7)) * 8),
                    (char*)&Abuf[cur][0] + off);
            gload16(Bm + (n0 + row) * 512 + kt * 64 + ((slot ^ (row & 7)) * 8),
                    (char*)&Bbuf[cur][0] + off);
        }
    };

    f32x4 acc[2][2];
#pragma unroll
    for (int mi = 0; mi < 2; ++mi)
#pragma unroll
        for (int ni = 0; ni < 2; ++ni) acc[mi][ni] = (f32x4){0.f, 0.f, 0.f, 0.f};

    STAGE(0, 0);
    int cur = 0;
    for (int kt = 0; kt < 8; ++kt) {
        __syncthreads();
        if (kt + 1 < 8) STAGE(kt + 1, cur ^ 1);
#pragma unroll
        for (int kk = 0; kk < 2; ++kk) {
            bf16x8 af[2], bfr[2];
#pragma unroll
            for (int mi = 0; mi < 2; ++mi) {
                const int row = wr * 32 + mi * 16 + c;
                af[mi] = *(const bf16x8*)&Abuf[cur][row * 64 + ((g + 4 * kk) ^ (row & 7)) * 8];
            }
#pragma unroll
            for (int ni = 0; ni < 2; ++ni) {
                const int row = wc * 32 + ni * 16 + c;
                bfr[ni] = *(const bf16x8*)&Bbuf[cur][row * 64 + ((g + 4 * kk) ^ (row & 7)) * 8];
            }
#pragma unroll
            for (int mi = 0; mi < 2; ++mi)
#pragma unroll
                for (int ni = 0; ni < 2; ++ni)
                    acc[mi][ni] = __builtin_amdgcn_mfma_f32_16x16x32_bf16(af[mi], bfr[ni], acc[mi][ni], 0, 0, 0);
        }
        cur ^= 1;
    }

#pragma unroll
    for (int mi = 0; mi < 2; ++mi)
#pragma unroll
        for (int ni = 0; ni < 2; ++ni) {
            const int col = n0 + wc * 32 + ni * 16 + c;
            const float bv = bias[col];
#pragma unroll
            for (int r = 0; r < 4; ++r) {
                const int p = m0 + wr * 32 + mi * 16 + 4 * g + r;
                out[p * 512 + col] = acc[mi][ni][r] + bv;
            }
        }
}

extern "C" void kernel_launch(void* const* d_in, const int* in_sizes, int n_in,
                              void* d_out, int out_size, void* d_ws, size_t ws_size,
                              hipStream_t stream) {
    const float* features = (const float*)d_in[0];
    const float* coords   = (const float*)d_in[1];
    const float* qkv_w    = (const float*)d_in[2];
    const float* proj_w   = (const float*)d_in[3];
    const float* proj_b   = (const float*)d_in[4];
    const float* pos_w    = (const float*)d_in[5];
    const float* pos_b    = (const float*)d_in[6];
    float* out = (float*)d_out;

    float* pos_ws = (float*)d_ws;                                    // 163840 f32
    unsigned short* feat_bf  = (unsigned short*)(pos_ws + TOTAL * 64);
    unsigned short* qkvw_bf  = feat_bf + 2560 * 512;
    unsigned short* projw_bf = qkvw_bf + 1536 * 512;
    unsigned short* q_ws  = projw_bf + 512 * 512;
    unsigned short* k_ws  = q_ws  + 8 * TOTAL * 64;
    unsigned short* vt_ws = k_ws  + 8 * TOTAL * 64;
    float* o_part = (float*)(vt_ws + 8 * TOTAL * 64);                // 2 * 2560*512 f32
    float2* ml2   = (float2*)(o_part + 2 * TOTAL * 512);             // 2 * 2560*8 float2
    unsigned short* y_bf = (unsigned short*)(ml2 + 2 * TOTAL * 8);   // 2560*512 bf16

    pos_kernel<<<dim3(TOTAL / 4), dim3(256), 0, stream>>>(coords, pos_w, pos_b, pos_ws);
    cast_kernel<<<dim3(1152), dim3(256), 0, stream>>>(
        features, qkv_w, proj_w, feat_bf, qkvw_bf, projw_bf);
    qkv_mfma_kernel<<<dim3(40, 24), dim3(256), 0, stream>>>(
        feat_bf, qkvw_bf, pos_ws, q_ws, k_ws, vt_ws);
    attn_part_kernel<<<dim3(288), dim3(256), 0, stream>>>(
        q_ws, k_ws, vt_ws, o_part, ml2);
    combine_kernel<<<dim3(640), dim3(256), 0, stream>>>(o_part, ml2, y_bf);
    proj_mfma_kernel<<<dim3(40, 8), dim3(256), 0, stream>>>(
        y_bf, projw_bf, proj_b, out);
}

// Round 13
// 72.661 us; speedup vs baseline: 1.5641x; 1.1046x over previous
//
#include <hip/hip_runtime.h>
#include <math.h>

#define TOTAL 2560
#define NEG_BIG (-1e30f)
#define LOG2E_8 0.18033688011112042f   // 0.125 * log2(e)

typedef __bf16 bf16x8 __attribute__((ext_vector_type(8)));
typedef float f32x4 __attribute__((ext_vector_type(4)));
typedef unsigned short ushort8v __attribute__((ext_vector_type(8)));
typedef unsigned short ushort4v __attribute__((ext_vector_type(4)));

__device__ inline unsigned short f2bf(float f) {
    unsigned u = __builtin_bit_cast(unsigned, f);
    u += 0x7fff + ((u >> 16) & 1);
    return (unsigned short)(u >> 16);
}

__device__ inline void gload16(const void* g, void* l) {
    __builtin_amdgcn_global_load_lds(
        (const __attribute__((address_space(1))) void*)g,
        (__attribute__((address_space(3))) void*)l, 16, 0, 0);
}

// ---------------- positional encoding (4 points / block) ----------------
__global__ __launch_bounds__(256) void pos_kernel(
    const float* __restrict__ coords,
    const float* __restrict__ pos_w,
    const float* __restrict__ pos_b,
    float* __restrict__ pos_out)
{
    __shared__ float enc[4][100];
    const int wv   = threadIdx.x >> 6;
    const int lane = threadIdx.x & 63;
    const int p = blockIdx.x * 4 + wv;
    const float c0 = coords[p * 3 + 0];
    const float c1 = coords[p * 3 + 1];
    const float c2 = coords[p * 3 + 2];
    for (int i = lane; i < 99; i += 64) {
        float v;
        if (i < 96) {
            const int d = i >> 5;
            const int j = i & 31;
            const float cv = (d == 0) ? c0 : ((d == 1) ? c1 : c2);
            const float freq = exp2f((float)(j & 15)) * 3.14159265358979323846f;
            const float sc = cv * freq;
            v = (j < 16) ? sinf(sc) : cosf(sc);
        } else {
            v = (i == 96) ? c0 : ((i == 97) ? c1 : c2);
        }
        enc[wv][i] = v;
    }
    float acc = pos_b[lane];
    const float* w = pos_w + lane * 99;
    for (int i = 0; i < 99; ++i) acc = fmaf(enc[wv][i], w[i], acc);
    pos_out[p * 64 + lane] = acc;
}

// ---------------- fp32 -> bf16 cast (features, qkv_w, proj_w) ----------------
__global__ __launch_bounds__(256) void cast_kernel(
    const float* __restrict__ f,  const float* __restrict__ qw, const float* __restrict__ pw,
    unsigned short* __restrict__ fb, unsigned short* __restrict__ qwb, unsigned short* __restrict__ pwb)
{
    const int s = blockIdx.x * 256 + threadIdx.x;
    const float* src; unsigned short* dst; int ls;
    if (s < 163840)      { src = f;  dst = fb;  ls = s; }
    else if (s < 262144) { src = qw; dst = qwb; ls = s - 163840; }
    else                 { src = pw; dst = pwb; ls = s - 262144; }
    const float4 x0 = *(const float4*)(src + ls * 8);
    const float4 x1 = *(const float4*)(src + ls * 8 + 4);
    ushort8v o;
    o[0] = f2bf(x0.x); o[1] = f2bf(x0.y); o[2] = f2bf(x0.z); o[3] = f2bf(x0.w);
    o[4] = f2bf(x1.x); o[5] = f2bf(x1.y); o[6] = f2bf(x1.z); o[7] = f2bf(x1.w);
    *(ushort8v*)(dst + ls * 8) = o;
}

// ---------------- QKV GEMM: bf16 MFMA, 64x64 tile, gload_lds dbuf (proven) ----
__global__ __launch_bounds__(256) void qkv_mfma_kernel(
    const unsigned short* __restrict__ A,
    const unsigned short* __restrict__ Bm,
    const float* __restrict__ pos,
    unsigned short* __restrict__ q_ws,
    unsigned short* __restrict__ k_ws,
    unsigned short* __restrict__ vt_ws)
{
    __shared__ unsigned short Abuf[2][64 * 64];
    __shared__ unsigned short Bbuf[2][64 * 64];
    const int m0 = blockIdx.x * 64;
    const int n0 = blockIdx.y * 64;
    const int t = threadIdx.x;
    const int w = t >> 6, lane = t & 63;
    const int wr = w >> 1, wc = w & 1;
    const int c = lane & 15, g = lane >> 4;

    auto STAGE = [&](int kt, int cur) {
#pragma unroll
        for (int i = 0; i < 2; ++i) {
            const int off = w * 2048 + i * 1024;
            const int ba  = off + lane * 16;
            const int row = ba >> 7;
            const int slot = (ba & 127) >> 4;
            gload16(A  + (m0 + row) * 512 + kt * 64 + ((slot ^ (row & 7)) * 8),
                    (char*)&Abuf[cur][0] + off);
            gload16(Bm + (n0 + row) * 512 + kt * 64 + ((slot ^ (row & 7)) * 8),
                    (char*)&Bbuf[cur][0] + off);
        }
    };

    f32x4 acc[2][2];
#pragma unroll
    for (int mi = 0; mi < 2; ++mi)
#pragma unroll
        for (int ni = 0; ni < 2; ++ni) acc[mi][ni] = (f32x4){0.f, 0.f, 0.f, 0.f};

    STAGE(0, 0);
    int cur = 0;
    for (int kt = 0; kt < 8; ++kt) {
        __syncthreads();
        if (kt + 1 < 8) STAGE(kt + 1, cur ^ 1);
#pragma unroll
        for (int kk = 0; kk < 2; ++kk) {
            bf16x8 af[2], bfr[2];
#pragma unroll
            for (int mi = 0; mi < 2; ++mi) {
                const int row = wr * 32 + mi * 16 + c;
                af[mi] = *(const bf16x8*)&Abuf[cur][row * 64 + ((g + 4 * kk) ^ (row & 7)) * 8];
            }
#pragma unroll
            for (int ni = 0; ni < 2; ++ni) {
                const int row = wc * 32 + ni * 16 + c;
                bfr[ni] = *(const bf16x8*)&Bbuf[cur][row * 64 + ((g + 4 * kk) ^ (row & 7)) * 8];
            }
#pragma unroll
            for (int mi = 0; mi < 2; ++mi)
#pragma unroll
                for (int ni = 0; ni < 2; ++ni)
                    acc[mi][ni] = __builtin_amdgcn_mfma_f32_16x16x32_bf16(af[mi], bfr[ni], acc[mi][ni], 0, 0, 0);
        }
        cur ^= 1;
    }

    const int which = n0 >> 9;
    const int h = (n0 >> 6) & 7;
#pragma unroll
    for (int mi = 0; mi < 2; ++mi)
#pragma unroll
        for (int ni = 0; ni < 2; ++ni) {
            const int dd = wc * 32 + ni * 16 + c;
            const int p0 = m0 + wr * 32 + mi * 16 + 4 * g;
            if (which == 2) {
                ushort4v o4;
#pragma unroll
                for (int r = 0; r < 4; ++r) o4[r] = f2bf(acc[mi][ni][r]);
                *(ushort4v*)(vt_ws + (h * 64 + dd) * TOTAL + p0) = o4;
            } else {
#pragma unroll
                for (int r = 0; r < 4; ++r) {
                    const int p = p0 + r;
                    const float v = acc[mi][ni][r] + pos[p * 64 + dd];
                    const int idx = (h * TOTAL + p) * 64 + dd;
                    if (which == 0) q_ws[idx] = f2bf(v);
                    else            k_ws[idx] = f2bf(v);
                }
            }
        }
}

// ---------------- flash attention: R10 loop, balanced 256-block folding -------
// grid 256 = 8h x 32qt (batch1). Blocks with qt<8 additionally run batch0's
// (h,qt) tile as a sequential phase (their batch1 loop skips 4 masked tiles),
// so EVERY block does exactly 16 k-tiles -> perfect CU load balance.
__global__ __launch_bounds__(256) void attn_kernel(
    const unsigned short* __restrict__ q_ws,
    const unsigned short* __restrict__ k_ws,
    const unsigned short* __restrict__ vt_ws,
    unsigned short* __restrict__ y)
{
    const int bx = blockIdx.x;
    const int h  = bx >> 5;
    const int qt = bx & 31;

    const int t    = threadIdx.x;
    const int w    = t >> 6;
    const int lane = t & 63;
    const int g    = lane >> 4;
    const int c    = lane & 15;

    __shared__ unsigned short Kbuf[2][128 * 64];   // [key][d], swizzled slots
    __shared__ unsigned short Vbuf[2][64 * 128];   // [d][key], swizzled slots
    __shared__ unsigned short P_lds[64][72];       // [q][k-half], wave-local rows

    const int nphase = (qt < 8) ? 2 : 1;

    for (int phase = 0; phase < nphase; ++phase) {
        // phase 0: batch1 (base 512, 16 k-tiles, kt0 skips masked); phase 1: batch0.
        const int base = phase ? 0 : 512;
        const int nkt  = phase ? 4 : 16;
        const int kt0  = (!phase && qt < 8) ? 4 : 0;
        const float extra = phase ? 1536.0f : 0.0f;

        const unsigned short* Kg = k_ws + (h * TOTAL + base) * 64;
        const unsigned short* Vg = vt_ws + h * 64 * TOTAL + base;

        const unsigned short* Qrow = q_ws + ((h * TOTAL) + base + qt * 64 + 16 * w + c) * 64;
        const bf16x8 qa0 = *(const bf16x8*)(Qrow + 8 * g);
        const bf16x8 qa1 = *(const bf16x8*)(Qrow + 8 * g + 32);

        float m_old = NEG_BIG, l_old = 0.f;     // state for q = 16w + c (lane-local)
        f32x4 o_acc[4];
#pragma unroll
        for (int n = 0; n < 4; ++n) o_acc[n] = (f32x4){0.f, 0.f, 0.f, 0.f};

        auto STAGE = [&](int kt, int cur) {
#pragma unroll
            for (int i = 0; i < 4; ++i) {
                const int off = w * 4096 + i * 1024;
                const int ba  = off + lane * 16;
                {   // K: 128 rows x 128 B
                    const int row = ba >> 7, slot = (ba & 127) >> 4;
                    gload16(Kg + (kt * 128 + row) * 64 + ((slot ^ (row & 7)) * 8),
                            (char*)&Kbuf[cur][0] + off);
                }
                {   // V: 64 rows x 256 B
                    const int dd = ba >> 8, slot = (ba & 255) >> 4;
                    gload16(Vg + dd * TOTAL + kt * 128 + ((slot ^ (dd & 7)) * 8),
                            (char*)&Vbuf[cur][0] + off);
                }
            }
        };

        if (phase) __syncthreads();   // all waves done reading LDS before reuse
        STAGE(kt0, 0);
        int cur = 0;
        for (int kt = kt0; kt < nkt; ++kt) {
            __syncthreads();   // drains vmcnt(0): buf[cur] ready
            if (kt + 1 < nkt) STAGE(kt + 1, cur ^ 1);

            const unsigned short* Ksh = &Kbuf[cur][0];
            const unsigned short* Vsh = &Vbuf[cur][0];

            // S^T via swapped operands: s_acc[n][r] = S[q=16w+c][k=16n+4g+r]
            f32x4 s_acc[8];
#pragma unroll
            for (int n = 0; n < 8; ++n) {
                f32x4 acc = (f32x4){0.f, 0.f, 0.f, 0.f};
                const int row = 16 * n + c;
                const bf16x8 kb0 = *(const bf16x8*)&Ksh[row * 64 + ((g + 0) ^ (c & 7)) * 8];
                const bf16x8 kb1 = *(const bf16x8*)&Ksh[row * 64 + ((g + 4) ^ (c & 7)) * 8];
                acc = __builtin_amdgcn_mfma_f32_16x16x32_bf16(kb0, qa0, acc, 0, 0, 0);
                acc = __builtin_amdgcn_mfma_f32_16x16x32_bf16(kb1, qa1, acc, 0, 0, 0);
                s_acc[n] = acc;
            }

            // lane-local softmax over 32 in-register values + 2 lane-hop reduces
            float mx01, mx23;
            {
                f32x4 m4 = s_acc[0];
#pragma unroll
                for (int n = 1; n < 8; ++n) {
#pragma unroll
                    for (int r = 0; r < 4; ++r) m4[r] = fmaxf(m4[r], s_acc[n][r]);
                }
                mx01 = fmaxf(m4[0], m4[1]); mx23 = fmaxf(m4[2], m4[3]);
            }
            float tm = fmaxf(mx01, mx23) * LOG2E_8;
            tm = fmaxf(tm, __shfl_xor(tm, 16));
            tm = fmaxf(tm, __shfl_xor(tm, 32));
            const float m_new = fmaxf(m_old, tm);
            const float corr = exp2f(m_old - m_new);
            float rs = 0.f;
#pragma unroll
            for (int n = 0; n < 8; ++n)
#pragma unroll
                for (int r = 0; r < 4; ++r) {
                    const float pv = exp2f(fmaf(s_acc[n][r], LOG2E_8, -m_new));
                    s_acc[n][r] = pv;
                    rs += pv;
                }
            rs += __shfl_xor(rs, 16);
            rs += __shfl_xor(rs, 32);
            l_old = l_old * corr + rs;
            m_old = m_new;

            // rescale o_acc rows (q = 16w+4g+r): fetch corr from owner lanes
            float corr_r[4];
#pragma unroll
            for (int r = 0; r < 4; ++r) corr_r[r] = __shfl(corr, 4 * g + r);
#pragma unroll
            for (int n = 0; n < 4; ++n)
#pragma unroll
                for (int r = 0; r < 4; ++r) o_acc[n][r] *= corr_r[r];

            // PV in two 64-key halves through P_lds (wave-local rows)
#pragma unroll
            for (int half = 0; half < 2; ++half) {
#pragma unroll
                for (int n = 0; n < 4; ++n) {
                    ushort4v pk;
#pragma unroll
                    for (int r = 0; r < 4; ++r) pk[r] = f2bf(s_acc[half * 4 + n][r]);
                    *(ushort4v*)&P_lds[16 * w + c][16 * n + 4 * g] = pk;
                }
#pragma unroll
                for (int kk = 0; kk < 2; ++kk) {
                    const bf16x8 pa = *(const bf16x8*)&P_lds[16 * w + c][8 * g + 32 * kk];
                    const int vslot = (g + 4 * (half * 2 + kk)) ^ (c & 7);
#pragma unroll
                    for (int n = 0; n < 4; ++n) {
                        const bf16x8 vb = *(const bf16x8*)&Vbuf[cur][(16 * n + c) * 128 + vslot * 8];
                        o_acc[n] = __builtin_amdgcn_mfma_f32_16x16x32_bf16(pa, vb, o_acc[n], 0, 0, 0);
                    }
                }
            }
            (void)Vsh;
            cur ^= 1;
        }

        // finalize: analytic zero-score keys (phase 1) + normalize
        float inv_own;
        if (extra > 0.f) {
            const float mn  = fmaxf(m_old, 0.f);
            const float ccf = exp2f(m_old - mn);
            const float l   = l_old * ccf + extra * exp2f(-mn);
            inv_own = ccf / l;
        } else {
            inv_own = 1.0f / l_old;
        }
        float inv_r[4];
#pragma unroll
        for (int r = 0; r < 4; ++r) inv_r[r] = __shfl(inv_own, 4 * g + r);
        unsigned short* yb = y + (base + qt * 64 + 16 * w) * 512 + h * 64;
#pragma unroll
        for (int n = 0; n < 4; ++n)
#pragma unroll
            for (int r = 0; r < 4; ++r)
                yb[(4 * g + r) * 512 + 16 * n + c] = f2bf(o_acc[n][r] * inv_r[r]);
    }
}

// ---------------- output projection: bf16 MFMA, 64x64 tile (proven) -----------
__global__ __launch_bounds__(256) void proj_mfma_kernel(
    const unsigned short* __restrict__ A,    // y_bf [2560][512]
    const unsigned short* __restrict__ Bm,   // projw_bf [512][512]
    const float* __restrict__ bias,
    float* __restrict__ out)
{
    __shared__ unsigned short Abuf[2][64 * 64];
    __shared__ unsigned short Bbuf[2][64 * 64];
    const int m0 = blockIdx.x * 64;
    const int n0 = blockIdx.y * 64;
    const int t = threadIdx.x;
    const int w = t >> 6, lane = t & 63;
    const int wr = w >> 1, wc = w & 1;
    const int c = lane & 15, g = lane >> 4;

    auto STAGE = [&](int kt, int cur) {
#pragma unroll
        for (int i = 0; i < 2; ++i) {
            const int off = w * 2048 + i * 1024;
            const int ba  = off + lane * 16;
            const int row = ba >> 7;
            const int slot = (ba & 127) >> 4;
            gload16(A  + (m0 + row) * 512 + kt * 64 + ((slot ^ (row & 7)) * 8),
                    (char*)&Abuf[cur][0] + off);
            gload16(Bm + (n0 + row) * 512 + kt * 64 + ((slot ^ (row & 7)) * 8),
                    (char*)&Bbuf[cur][0] + off);
        }
    };

    f32x4 acc[2][2];
#pragma unroll
    for (int mi = 0; mi < 2; ++mi)
#pragma unroll
        for (int ni = 0; ni < 2; ++ni) acc[mi][ni] = (f32x4){0.f, 0.f, 0.f, 0.f};

    STAGE(0, 0);
    int cur = 0;
    for (int kt = 0; kt < 8; ++kt) {
        __syncthreads();
        if (kt + 1 < 8) STAGE(kt + 1, cur ^ 1);
#pragma unroll
        for (int kk = 0; kk < 2; ++kk) {
            bf16x8 af[2], bfr[2];
#pragma unroll
            for (int mi = 0; mi < 2; ++mi) {
                const int row = wr * 32 + mi * 16 + c;
                af[mi] = *(const bf16x8*)&Abuf[cur][row * 64 + ((g + 4 * kk) ^ (row & 7)) * 8];
            }
#pragma unroll
            for (int ni = 0; ni < 2; ++ni) {
                const int row = wc * 32 + ni * 16 + c;
                bfr[ni] = *(const bf16x8*)&Bbuf[cur][row * 64 + ((g + 4 * kk) ^ (row & 7)) * 8];
            }
#pragma unroll
            for (int mi = 0; mi < 2; ++mi)
#pragma unroll
                for (int ni = 0; ni < 2; ++ni)
                    acc[mi][ni] = __builtin_amdgcn_mfma_f32_16x16x32_bf16(af[mi], bfr[ni], acc[mi][ni], 0, 0, 0);
        }
        cur ^= 1;
    }

#pragma unroll
    for (int mi = 0; mi < 2; ++mi)
#pragma unroll
        for (int ni = 0; ni < 2; ++ni) {
            const int col = n0 + wc * 32 + ni * 16 + c;
            const float bv = bias[col];
#pragma unroll
            for (int r = 0; r < 4; ++r) {
                const int p = m0 + wr * 32 + mi * 16 + 4 * g + r;
                out[p * 512 + col] = acc[mi][ni][r] + bv;
            }
        }
}

extern "C" void kernel_launch(void* const* d_in, const int* in_sizes, int n_in,
                              void* d_out, int out_size, void* d_ws, size_t ws_size,
                              hipStream_t stream) {
    const float* features = (const float*)d_in[0];
    const float* coords   = (const float*)d_in[1];
    const float* qkv_w    = (const float*)d_in[2];
    const float* proj_w   = (const float*)d_in[3];
    const float* proj_b   = (const float*)d_in[4];
    const float* pos_w    = (const float*)d_in[5];
    const float* pos_b    = (const float*)d_in[6];
    float* out = (float*)d_out;

    float* pos_ws = (float*)d_ws;                                    // 163840 f32
    unsigned short* feat_bf  = (unsigned short*)(pos_ws + TOTAL * 64);
    unsigned short* qkvw_bf  = feat_bf + 2560 * 512;
    unsigned short* projw_bf = qkvw_bf + 1536 * 512;
    unsigned short* q_ws  = projw_bf + 512 * 512;
    unsigned short* k_ws  = q_ws  + 8 * TOTAL * 64;
    unsigned short* vt_ws = k_ws  + 8 * TOTAL * 64;
    unsigned short* y_bf  = vt_ws + 8 * TOTAL * 64;                  // 2560*512 bf16

    pos_kernel<<<dim3(TOTAL / 4), dim3(256), 0, stream>>>(coords, pos_w, pos_b, pos_ws);
    cast_kernel<<<dim3(1152), dim3(256), 0, stream>>>(
        features, qkv_w, proj_w, feat_bf, qkvw_bf, projw_bf);
    qkv_mfma_kernel<<<dim3(40, 24), dim3(256), 0, stream>>>(
        feat_bf, qkvw_bf, pos_ws, q_ws, k_ws, vt_ws);
    attn_kernel<<<dim3(256), dim3(256), 0, stream>>>(q_ws, k_ws, vt_ws, y_bf);
    proj_mfma_kernel<<<dim3(40, 8), dim3(256), 0, stream>>>(
        y_bf, projw_bf, proj_b, out);
}

// Round 14
// 66.557 us; speedup vs baseline: 1.7075x; 1.0917x over previous
//
#include <hip/hip_runtime.h>
#include <math.h>

#define TOTAL 2560
#define NEG_BIG (-1e30f)
#define LOG2E_8 0.18033688011112042f   // 0.125 * log2(e)

typedef __bf16 bf16x8 __attribute__((ext_vector_type(8)));
typedef float f32x4 __attribute__((ext_vector_type(4)));
typedef unsigned short ushort8v __attribute__((ext_vector_type(8)));
typedef unsigned short ushort4v __attribute__((ext_vector_type(4)));

__device__ inline unsigned short f2bf(float f) {
    unsigned u = __builtin_bit_cast(unsigned, f);
    u += 0x7fff + ((u >> 16) & 1);
    return (unsigned short)(u >> 16);
}

__device__ inline void gload16(const void* g, void* l) {
    __builtin_amdgcn_global_load_lds(
        (const __attribute__((address_space(1))) void*)g,
        (__attribute__((address_space(3))) void*)l, 16, 0, 0);
}

// ---------------- positional encoding (4 points / block) ----------------
__global__ __launch_bounds__(256) void pos_kernel(
    const float* __restrict__ coords,
    const float* __restrict__ pos_w,
    const float* __restrict__ pos_b,
    float* __restrict__ pos_out)
{
    __shared__ float enc[4][100];
    const int wv   = threadIdx.x >> 6;
    const int lane = threadIdx.x & 63;
    const int p = blockIdx.x * 4 + wv;
    const float c0 = coords[p * 3 + 0];
    const float c1 = coords[p * 3 + 1];
    const float c2 = coords[p * 3 + 2];
    for (int i = lane; i < 99; i += 64) {
        float v;
        if (i < 96) {
            const int d = i >> 5;
            const int j = i & 31;
            const float cv = (d == 0) ? c0 : ((d == 1) ? c1 : c2);
            const float freq = exp2f((float)(j & 15)) * 3.14159265358979323846f;
            const float sc = cv * freq;
            v = (j < 16) ? sinf(sc) : cosf(sc);
        } else {
            v = (i == 96) ? c0 : ((i == 97) ? c1 : c2);
        }
        enc[wv][i] = v;
    }
    float acc = pos_b[lane];
    const float* w = pos_w + lane * 99;
    for (int i = 0; i < 99; ++i) acc = fmaf(enc[wv][i], w[i], acc);
    pos_out[p * 64 + lane] = acc;
}

// ---------------- fp32 -> bf16 cast (features, qkv_w, proj_w) ----------------
__global__ __launch_bounds__(256) void cast_kernel(
    const float* __restrict__ f,  const float* __restrict__ qw, const float* __restrict__ pw,
    unsigned short* __restrict__ fb, unsigned short* __restrict__ qwb, unsigned short* __restrict__ pwb)
{
    const int s = blockIdx.x * 256 + threadIdx.x;
    const float* src; unsigned short* dst; int ls;
    if (s < 163840)      { src = f;  dst = fb;  ls = s; }
    else if (s < 262144) { src = qw; dst = qwb; ls = s - 163840; }
    else                 { src = pw; dst = pwb; ls = s - 262144; }
    const float4 x0 = *(const float4*)(src + ls * 8);
    const float4 x1 = *(const float4*)(src + ls * 8 + 4);
    ushort8v o;
    o[0] = f2bf(x0.x); o[1] = f2bf(x0.y); o[2] = f2bf(x0.z); o[3] = f2bf(x0.w);
    o[4] = f2bf(x1.x); o[5] = f2bf(x1.y); o[6] = f2bf(x1.z); o[7] = f2bf(x1.w);
    *(ushort8v*)(dst + ls * 8) = o;
}

// ---------------- QKV GEMM: bf16 MFMA, 64x64 tile, gload_lds dbuf (proven) ----
__global__ __launch_bounds__(256) void qkv_mfma_kernel(
    const unsigned short* __restrict__ A,
    const unsigned short* __restrict__ Bm,
    const float* __restrict__ pos,
    unsigned short* __restrict__ q_ws,
    unsigned short* __restrict__ k_ws,
    unsigned short* __restrict__ vt_ws)
{
    __shared__ unsigned short Abuf[2][64 * 64];
    __shared__ unsigned short Bbuf[2][64 * 64];
    const int m0 = blockIdx.x * 64;
    const int n0 = blockIdx.y * 64;
    const int t = threadIdx.x;
    const int w = t >> 6, lane = t & 63;
    const int wr = w >> 1, wc = w & 1;
    const int c = lane & 15, g = lane >> 4;

    auto STAGE = [&](int kt, int cur) {
#pragma unroll
        for (int i = 0; i < 2; ++i) {
            const int off = w * 2048 + i * 1024;
            const int ba  = off + lane * 16;
            const int row = ba >> 7;
            const int slot = (ba & 127) >> 4;
            gload16(A  + (m0 + row) * 512 + kt * 64 + ((slot ^ (row & 7)) * 8),
                    (char*)&Abuf[cur][0] + off);
            gload16(Bm + (n0 + row) * 512 + kt * 64 + ((slot ^ (row & 7)) * 8),
                    (char*)&Bbuf[cur][0] + off);
        }
    };

    f32x4 acc[2][2];
#pragma unroll
    for (int mi = 0; mi < 2; ++mi)
#pragma unroll
        for (int ni = 0; ni < 2; ++ni) acc[mi][ni] = (f32x4){0.f, 0.f, 0.f, 0.f};

    STAGE(0, 0);
    int cur = 0;
    for (int kt = 0; kt < 8; ++kt) {
        __syncthreads();
        if (kt + 1 < 8) STAGE(kt + 1, cur ^ 1);
#pragma unroll
        for (int kk = 0; kk < 2; ++kk) {
            bf16x8 af[2], bfr[2];
#pragma unroll
            for (int mi = 0; mi < 2; ++mi) {
                const int row = wr * 32 + mi * 16 + c;
                af[mi] = *(const bf16x8*)&Abuf[cur][row * 64 + ((g + 4 * kk) ^ (row & 7)) * 8];
            }
#pragma unroll
            for (int ni = 0; ni < 2; ++ni) {
                const int row = wc * 32 + ni * 16 + c;
                bfr[ni] = *(const bf16x8*)&Bbuf[cur][row * 64 + ((g + 4 * kk) ^ (row & 7)) * 8];
            }
#pragma unroll
            for (int mi = 0; mi < 2; ++mi)
#pragma unroll
                for (int ni = 0; ni < 2; ++ni)
                    acc[mi][ni] = __builtin_amdgcn_mfma_f32_16x16x32_bf16(af[mi], bfr[ni], acc[mi][ni], 0, 0, 0);
        }
        cur ^= 1;
    }

    const int which = n0 >> 9;
    const int h = (n0 >> 6) & 7;
#pragma unroll
    for (int mi = 0; mi < 2; ++mi)
#pragma unroll
        for (int ni = 0; ni < 2; ++ni) {
            const int dd = wc * 32 + ni * 16 + c;
            const int p0 = m0 + wr * 32 + mi * 16 + 4 * g;
            if (which == 2) {
                ushort4v o4;
#pragma unroll
                for (int r = 0; r < 4; ++r) o4[r] = f2bf(acc[mi][ni][r]);
                *(ushort4v*)(vt_ws + (h * 64 + dd) * TOTAL + p0) = o4;
            } else {
#pragma unroll
                for (int r = 0; r < 4; ++r) {
                    const int p = p0 + r;
                    const float v = acc[mi][ni][r] + pos[p * 64 + dd];
                    const int idx = (h * TOTAL + p) * 64 + dd;
                    if (which == 0) q_ws[idx] = f2bf(v);
                    else            k_ws[idx] = f2bf(v);
                }
            }
        }
}

// ---------------- flash attention: KVBLK=256, K restage + V dbuf, defer-max ---
// grid 256 = 8h x 32qt. qt<8 blocks: batch1 (skip 2 masked 256-tiles, 6 tiles)
// + batch0 (2 tiles) = 8 tiles; qt>=8: 8 tiles. Perfect balance, 1 block/CU.
// Per tile: barA (K,V ready) -> QK -> barB -> restage K(t+1) -> softmax
// (defer-max) -> stage V(t+1, other buf) -> PV.
__global__ __launch_bounds__(256) void attn_kernel(
    const unsigned short* __restrict__ q_ws,
    const unsigned short* __restrict__ k_ws,
    const unsigned short* __restrict__ vt_ws,
    unsigned short* __restrict__ y)
{
    const int bx = blockIdx.x;
    const int h  = bx >> 5;
    const int qt = bx & 31;

    const int t    = threadIdx.x;
    const int w    = t >> 6;
    const int lane = t & 63;
    const int g    = lane >> 4;
    const int c    = lane & 15;
    const int c7   = c & 7;

    __shared__ unsigned short Kbuf[256 * 64];      // [key][d], swizzled slots, restaged
    __shared__ unsigned short Vbuf[2][64 * 256];   // [d][key], swizzled slots, dbuf
    __shared__ unsigned short P_lds[64][264];      // [q][key], wave-local rows

    const int nphase = (qt < 8) ? 2 : 1;
    int cur = 0;

    for (int phase = 0; phase < nphase; ++phase) {
        const int base = phase ? 0 : 512;
        const int nkt  = phase ? 2 : 8;            // 256-key tiles
        const int kt0  = (!phase && qt < 8) ? 2 : 0;
        const float extra = phase ? 1536.0f : 0.0f;

        const unsigned short* Kg = k_ws + (h * TOTAL + base) * 64;
        const unsigned short* Vg = vt_ws + h * 64 * TOTAL + base;

        const unsigned short* Qrow = q_ws + ((h * TOTAL) + base + qt * 64 + 16 * w + c) * 64;
        const bf16x8 qa0 = *(const bf16x8*)(Qrow + 8 * g);
        const bf16x8 qa1 = *(const bf16x8*)(Qrow + 8 * g + 32);

        float m_old = NEG_BIG, l_old = 0.f;        // stats for q = 16w + c
        f32x4 o_acc[4];
#pragma unroll
        for (int n = 0; n < 4; ++n) o_acc[n] = (f32x4){0.f, 0.f, 0.f, 0.f};

        // K tile: 256 rows x 128 B = 32 KB
        auto STAGE_K = [&](int kt) {
#pragma unroll
            for (int i = 0; i < 8; ++i) {
                const int off = w * 8192 + i * 1024;
                const int ba  = off + lane * 16;
                const int row = ba >> 7;
                const int slot = (ba & 127) >> 4;
                gload16(Kg + (kt * 256 + row) * 64 + ((slot ^ (row & 7)) * 8),
                        (char*)&Kbuf[0] + off);
            }
        };
        // V^T tile: 64 rows x 512 B = 32 KB
        auto STAGE_V = [&](int kt, int vb) {
#pragma unroll
            for (int i = 0; i < 8; ++i) {
                const int off = w * 8192 + i * 1024;
                const int ba  = off + lane * 16;
                const int dd  = ba >> 9;
                const int slot = (ba & 511) >> 4;
                gload16(Vg + dd * TOTAL + kt * 256 + ((slot ^ (dd & 7)) * 8),
                        (char*)&Vbuf[vb][0] + off);
            }
        };

        if (phase) __syncthreads();    // prior phase's LDS reads done before restage
        STAGE_K(kt0);
        STAGE_V(kt0, cur);

        for (int kt = kt0; kt < nkt; ++kt) {
            __syncthreads();           // A: drains vmcnt -> K(kt), V[cur] ready

            // QK: s_acc[n][r] = S[q=16w+c][k=16n+4g+r], n = 0..15
            f32x4 s_acc[16];
#pragma unroll
            for (int n = 0; n < 16; ++n) {
                const int row = 16 * n + c;
                const bf16x8 kb0 = *(const bf16x8*)&Kbuf[row * 64 + ((g + 0) ^ c7) * 8];
                const bf16x8 kb1 = *(const bf16x8*)&Kbuf[row * 64 + ((g + 4) ^ c7) * 8];
                f32x4 a = __builtin_amdgcn_mfma_f32_16x16x32_bf16(kb0, qa0, (f32x4){0.f,0.f,0.f,0.f}, 0, 0, 0);
                s_acc[n] = __builtin_amdgcn_mfma_f32_16x16x32_bf16(kb1, qa1, a, 0, 0, 0);
            }
            __syncthreads();           // B: QK's LDS reads retired -> K buffer free
            if (kt + 1 < nkt) STAGE_K(kt + 1);

            // softmax (exp2-domain) with defer-max (T13, THR=8)
            f32x4 m4 = s_acc[0];
#pragma unroll
            for (int n = 1; n < 16; ++n)
#pragma unroll
                for (int r = 0; r < 4; ++r) m4[r] = fmaxf(m4[r], s_acc[n][r]);
            float tm = fmaxf(fmaxf(m4[0], m4[1]), fmaxf(m4[2], m4[3])) * LOG2E_8;
            tm = fmaxf(tm, __shfl_xor(tm, 16));
            tm = fmaxf(tm, __shfl_xor(tm, 32));
            if (!__all(tm <= m_old + 8.0f)) {
                const float m_new = fmaxf(m_old, tm);
                const float corr = exp2f(m_old - m_new);
                float corr_r[4];
#pragma unroll
                for (int r = 0; r < 4; ++r) corr_r[r] = __shfl(corr, 4 * g + r);
#pragma unroll
                for (int n = 0; n < 4; ++n)
#pragma unroll
                    for (int r = 0; r < 4; ++r) o_acc[n][r] *= corr_r[r];
                l_old *= corr;
                m_old = m_new;
            }
            float rs = 0.f;
#pragma unroll
            for (int n = 0; n < 16; ++n)
#pragma unroll
                for (int r = 0; r < 4; ++r) {
                    const float pv = exp2f(fmaf(s_acc[n][r], LOG2E_8, -m_old));
                    s_acc[n][r] = pv;
                    rs += pv;
                }
            rs += __shfl_xor(rs, 16);
            rs += __shfl_xor(rs, 32);
            l_old += rs;

            // P write (wave-local rows; compiler orders ds_write->ds_read)
#pragma unroll
            for (int n = 0; n < 16; ++n) {
                ushort4v pk;
#pragma unroll
                for (int r = 0; r < 4; ++r) pk[r] = f2bf(s_acc[n][r]);
                *(ushort4v*)&P_lds[16 * w + c][16 * n + 4 * g] = pk;
            }

            if (kt + 1 < nkt) STAGE_V(kt + 1, cur ^ 1);   // overlap with PV below

            // PV: O += P V, k-slices kk = 0..7
#pragma unroll
            for (int kk = 0; kk < 8; ++kk) {
                const bf16x8 pa = *(const bf16x8*)&P_lds[16 * w + c][8 * g + 32 * kk];
                const int vslot = (g + 4 * kk) ^ c7;
#pragma unroll
                for (int n = 0; n < 4; ++n) {
                    const bf16x8 vb = *(const bf16x8*)&Vbuf[cur][(16 * n + c) * 256 + vslot * 8];
                    o_acc[n] = __builtin_amdgcn_mfma_f32_16x16x32_bf16(pa, vb, o_acc[n], 0, 0, 0);
                }
            }
            cur ^= 1;
        }

        // finalize: analytic zero-score keys (phase 1 / batch0) + normalize
        float inv_own;
        if (extra > 0.f) {
            const float mn  = fmaxf(m_old, 0.f);
            const float ccf = exp2f(m_old - mn);
            const float l   = l_old * ccf + extra * exp2f(-mn);
            inv_own = ccf / l;
        } else {
            inv_own = 1.0f / l_old;
        }
        float inv_r[4];
#pragma unroll
        for (int r = 0; r < 4; ++r) inv_r[r] = __shfl(inv_own, 4 * g + r);
        unsigned short* yb = y + (base + qt * 64 + 16 * w) * 512 + h * 64;
#pragma unroll
        for (int n = 0; n < 4; ++n)
#pragma unroll
            for (int r = 0; r < 4; ++r)
                yb[(4 * g + r) * 512 + 16 * n + c] = f2bf(o_acc[n][r] * inv_r[r]);
    }
}

// ---------------- output projection: bf16 MFMA, 64x64 tile (proven) -----------
__global__ __launch_bounds__(256) void proj_mfma_kernel(
    const unsigned short* __restrict__ A,    // y_bf [2560][512]
    const unsigned short* __restrict__ Bm,   // projw_bf [512][512]
    const float* __restrict__ bias,
    float* __restrict__ out)
{
    __shared__ unsigned short Abuf[2][64 * 64];
    __shared__ unsigned short Bbuf[2][64 * 64];
    const int m0 = blockIdx.x * 64;
    const int n0 = blockIdx.y * 64;
    const int t = threadIdx.x;
    const int w = t >> 6, lane = t & 63;
    const int wr = w >> 1, wc = w & 1;
    const int c = lane & 15, g = lane >> 4;

    auto STAGE = [&](int kt, int cur) {
#pragma unroll
        for (int i = 0; i < 2; ++i) {
            const int off = w * 2048 + i * 1024;
            const int ba  = off + lane * 16;
            const int row = ba >> 7;
            const int slot = (ba & 127) >> 4;
            gload16(A  + (m0 + row) * 512 + kt * 64 + ((slot ^ (row & 7)) * 8),
                    (char*)&Abuf[cur][0] + off);
            gload16(Bm + (n0 + row) * 512 + kt * 64 + ((slot ^ (row & 7)) * 8),
                    (char*)&Bbuf[cur][0] + off);
        }
    };

    f32x4 acc[2][2];
#pragma unroll
    for (int mi = 0; mi < 2; ++mi)
#pragma unroll
        for (int ni = 0; ni < 2; ++ni) acc[mi][ni] = (f32x4){0.f, 0.f, 0.f, 0.f};

    STAGE(0, 0);
    int cur = 0;
    for (int kt = 0; kt < 8; ++kt) {
        __syncthreads();
        if (kt + 1 < 8) STAGE(kt + 1, cur ^ 1);
#pragma unroll
        for (int kk = 0; kk < 2; ++kk) {
            bf16x8 af[2], bfr[2];
#pragma unroll
            for (int mi = 0; mi < 2; ++mi) {
                const int row = wr * 32 + mi * 16 + c;
                af[mi] = *(const bf16x8*)&Abuf[cur][row * 64 + ((g + 4 * kk) ^ (row & 7)) * 8];
            }
#pragma unroll
            for (int ni = 0; ni < 2; ++ni) {
                const int row = wc * 32 + ni * 16 + c;
                bfr[ni] = *(const bf16x8*)&Bbuf[cur][row * 64 + ((g + 4 * kk) ^ (row & 7)) * 8];
            }
#pragma unroll
            for (int mi = 0; mi < 2; ++mi)
#pragma unroll
                for (int ni = 0; ni < 2; ++ni)
                    acc[mi][ni] = __builtin_amdgcn_mfma_f32_16x16x32_bf16(af[mi], bfr[ni], acc[mi][ni], 0, 0, 0);
        }
        cur ^= 1;
    }

#pragma unroll
    for (int mi = 0; mi < 2; ++mi)
#pragma unroll
        for (int ni = 0; ni < 2; ++ni) {
            const int col = n0 + wc * 32 + ni * 16 + c;
            const float bv = bias[col];
#pragma unroll
            for (int r = 0; r < 4; ++r) {
                const int p = m0 + wr * 32 + mi * 16 + 4 * g + r;
                out[p * 512 + col] = acc[mi][ni][r] + bv;
            }
        }
}

extern "C" void kernel_launch(void* const* d_in, const int* in_sizes, int n_in,
                              void* d_out, int out_size, void* d_ws, size_t ws_size,
                              hipStream_t stream) {
    const float* features = (const float*)d_in[0];
    const float* coords   = (const float*)d_in[1];
    const float* qkv_w    = (const float*)d_in[2];
    const float* proj_w   = (const float*)d_in[3];
    const float* proj_b   = (const float*)d_in[4];
    const float* pos_w    = (const float*)d_in[5];
    const float* pos_b    = (const float*)d_in[6];
    float* out = (float*)d_out;

    float* pos_ws = (float*)d_ws;                                    // 163840 f32
    unsigned short* feat_bf  = (unsigned short*)(pos_ws + TOTAL * 64);
    unsigned short* qkvw_bf  = feat_bf + 2560 * 512;
    unsigned short* projw_bf = qkvw_bf + 1536 * 512;
    unsigned short* q_ws  = projw_bf + 512 * 512;
    unsigned short* k_ws  = q_ws  + 8 * TOTAL * 64;
    unsigned short* vt_ws = k_ws  + 8 * TOTAL * 64;
    unsigned short* y_bf  = vt_ws + 8 * TOTAL * 64;                  // 2560*512 bf16

    pos_kernel<<<dim3(TOTAL / 4), dim3(256), 0, stream>>>(coords, pos_w, pos_b, pos_ws);
    cast_kernel<<<dim3(1152), dim3(256), 0, stream>>>(
        features, qkv_w, proj_w, feat_bf, qkvw_bf, projw_bf);
    qkv_mfma_kernel<<<dim3(40, 24), dim3(256), 0, stream>>>(
        feat_bf, qkvw_bf, pos_ws, q_ws, k_ws, vt_ws);
    attn_kernel<<<dim3(256), dim3(256), 0, stream>>>(q_ws, k_ws, vt_ws, y_bf);
    proj_mfma_kernel<<<dim3(40, 8), dim3(256), 0, stream>>>(
        y_bf, projw_bf, proj_b, out);
}

// Round 15
// 64.410 us; speedup vs baseline: 1.7644x; 1.0333x over previous
//
#include <hip/hip_runtime.h>
#include <math.h>

#define TOTAL 2560
#define NEG_BIG (-1e30f)
#define LOG2E_8 0.18033688011112042f   // 0.125 * log2(e)

typedef __bf16 bf16x8 __attribute__((ext_vector_type(8)));
typedef float f32x4 __attribute__((ext_vector_type(4)));
typedef unsigned short ushort8v __attribute__((ext_vector_type(8)));
typedef unsigned short ushort4v __attribute__((ext_vector_type(4)));

__device__ inline unsigned short f2bf(float f) {
    unsigned u = __builtin_bit_cast(unsigned, f);
    u += 0x7fff + ((u >> 16) & 1);
    return (unsigned short)(u >> 16);
}

__device__ inline void gload16(const void* g, void* l) {
    __builtin_amdgcn_global_load_lds(
        (const __attribute__((address_space(1))) void*)g,
        (__attribute__((address_space(3))) void*)l, 16, 0, 0);
}

// ---------------- fused positional encoding + bf16 casts (R6-proven) ----------
// blocks [0,640): pos (4 points each). blocks [640,1792): casts.
__global__ __launch_bounds__(256) void pos_cast_kernel(
    const float* __restrict__ coords,
    const float* __restrict__ pos_w,
    const float* __restrict__ pos_b,
    const float* __restrict__ f,  const float* __restrict__ qw, const float* __restrict__ pw,
    float* __restrict__ pos_out,
    unsigned short* __restrict__ fb, unsigned short* __restrict__ qwb, unsigned short* __restrict__ pwb)
{
    const int bx = blockIdx.x;
    if (bx < 640) {
        __shared__ float enc[4][100];
        const int wv   = threadIdx.x >> 6;
        const int lane = threadIdx.x & 63;
        const int p = bx * 4 + wv;
        const float c0 = coords[p * 3 + 0];
        const float c1 = coords[p * 3 + 1];
        const float c2 = coords[p * 3 + 2];
        for (int i = lane; i < 99; i += 64) {
            float v;
            if (i < 96) {
                const int d = i >> 5;
                const int j = i & 31;
                const float cv = (d == 0) ? c0 : ((d == 1) ? c1 : c2);
                const float freq = exp2f((float)(j & 15)) * 3.14159265358979323846f;
                const float sc = cv * freq;
                v = (j < 16) ? sinf(sc) : cosf(sc);
            } else {
                v = (i == 96) ? c0 : ((i == 97) ? c1 : c2);
            }
            enc[wv][i] = v;
        }
        float acc = pos_b[lane];
        const float* w = pos_w + lane * 99;
        for (int i = 0; i < 99; ++i) acc = fmaf(enc[wv][i], w[i], acc);
        pos_out[p * 64 + lane] = acc;
    } else {
        const int s = (bx - 640) * 256 + threadIdx.x;
        const float* src; unsigned short* dst; int ls;
        if (s < 163840)      { src = f;  dst = fb;  ls = s; }
        else if (s < 262144) { src = qw; dst = qwb; ls = s - 163840; }
        else                 { src = pw; dst = pwb; ls = s - 262144; }
        const float4 x0 = *(const float4*)(src + ls * 8);
        const float4 x1 = *(const float4*)(src + ls * 8 + 4);
        ushort8v o;
        o[0] = f2bf(x0.x); o[1] = f2bf(x0.y); o[2] = f2bf(x0.z); o[3] = f2bf(x0.w);
        o[4] = f2bf(x1.x); o[5] = f2bf(x1.y); o[6] = f2bf(x1.z); o[7] = f2bf(x1.w);
        *(ushort8v*)(dst + ls * 8) = o;
    }
}

// ---------------- QKV GEMM: bf16 MFMA, 64x64 tile, gload_lds dbuf (proven) ----
__global__ __launch_bounds__(256) void qkv_mfma_kernel(
    const unsigned short* __restrict__ A,
    const unsigned short* __restrict__ Bm,
    const float* __restrict__ pos,
    unsigned short* __restrict__ q_ws,
    unsigned short* __restrict__ k_ws,
    unsigned short* __restrict__ vt_ws)
{
    __shared__ unsigned short Abuf[2][64 * 64];
    __shared__ unsigned short Bbuf[2][64 * 64];
    const int m0 = blockIdx.x * 64;
    const int n0 = blockIdx.y * 64;
    const int t = threadIdx.x;
    const int w = t >> 6, lane = t & 63;
    const int wr = w >> 1, wc = w & 1;
    const int c = lane & 15, g = lane >> 4;

    auto STAGE = [&](int kt, int cur) {
#pragma unroll
        for (int i = 0; i < 2; ++i) {
            const int off = w * 2048 + i * 1024;
            const int ba  = off + lane * 16;
            const int row = ba >> 7;
            const int slot = (ba & 127) >> 4;
            gload16(A  + (m0 + row) * 512 + kt * 64 + ((slot ^ (row & 7)) * 8),
                    (char*)&Abuf[cur][0] + off);
            gload16(Bm + (n0 + row) * 512 + kt * 64 + ((slot ^ (row & 7)) * 8),
                    (char*)&Bbuf[cur][0] + off);
        }
    };

    f32x4 acc[2][2];
#pragma unroll
    for (int mi = 0; mi < 2; ++mi)
#pragma unroll
        for (int ni = 0; ni < 2; ++ni) acc[mi][ni] = (f32x4){0.f, 0.f, 0.f, 0.f};

    STAGE(0, 0);
    int cur = 0;
    for (int kt = 0; kt < 8; ++kt) {
        __syncthreads();
        if (kt + 1 < 8) STAGE(kt + 1, cur ^ 1);
#pragma unroll
        for (int kk = 0; kk < 2; ++kk) {
            bf16x8 af[2], bfr[2];
#pragma unroll
            for (int mi = 0; mi < 2; ++mi) {
                const int row = wr * 32 + mi * 16 + c;
                af[mi] = *(const bf16x8*)&Abuf[cur][row * 64 + ((g + 4 * kk) ^ (row & 7)) * 8];
            }
#pragma unroll
            for (int ni = 0; ni < 2; ++ni) {
                const int row = wc * 32 + ni * 16 + c;
                bfr[ni] = *(const bf16x8*)&Bbuf[cur][row * 64 + ((g + 4 * kk) ^ (row & 7)) * 8];
            }
#pragma unroll
            for (int mi = 0; mi < 2; ++mi)
#pragma unroll
                for (int ni = 0; ni < 2; ++ni)
                    acc[mi][ni] = __builtin_amdgcn_mfma_f32_16x16x32_bf16(af[mi], bfr[ni], acc[mi][ni], 0, 0, 0);
        }
        cur ^= 1;
    }

    const int which = n0 >> 9;
    const int h = (n0 >> 6) & 7;
#pragma unroll
    for (int mi = 0; mi < 2; ++mi)
#pragma unroll
        for (int ni = 0; ni < 2; ++ni) {
            const int dd = wc * 32 + ni * 16 + c;
            const int p0 = m0 + wr * 32 + mi * 16 + 4 * g;
            if (which == 2) {
                ushort4v o4;
#pragma unroll
                for (int r = 0; r < 4; ++r) o4[r] = f2bf(acc[mi][ni][r]);
                *(ushort4v*)(vt_ws + (h * 64 + dd) * TOTAL + p0) = o4;
            } else {
#pragma unroll
                for (int r = 0; r < 4; ++r) {
                    const int p = p0 + r;
                    const float v = acc[mi][ni][r] + pos[p * 64 + dd];
                    const int idx = (h * TOTAL + p) * 64 + dd;
                    if (which == 0) q_ws[idx] = f2bf(v);
                    else            k_ws[idx] = f2bf(v);
                }
            }
        }
}

// ---------------- flash attention: KVBLK=256 (R14-proven) + XCD-local heads ---
// grid 256; h = bx & 7 so all 32 q-tile blocks of head h land on XCD h
// (default round-robin bx%8): that head's 512 KB K/V stays in one L2.
__global__ __launch_bounds__(256) void attn_kernel(
    const unsigned short* __restrict__ q_ws,
    const unsigned short* __restrict__ k_ws,
    const unsigned short* __restrict__ vt_ws,
    unsigned short* __restrict__ y)
{
    const int bx = blockIdx.x;
    const int h  = bx & 7;
    const int qt = bx >> 3;

    const int t    = threadIdx.x;
    const int w    = t >> 6;
    const int lane = t & 63;
    const int g    = lane >> 4;
    const int c    = lane & 15;
    const int c7   = c & 7;

    __shared__ unsigned short Kbuf[256 * 64];      // [key][d], swizzled slots, restaged
    __shared__ unsigned short Vbuf[2][64 * 256];   // [d][key], swizzled slots, dbuf
    __shared__ unsigned short P_lds[64][264];      // [q][key], wave-local rows

    const int nphase = (qt < 8) ? 2 : 1;
    int cur = 0;

    for (int phase = 0; phase < nphase; ++phase) {
        const int base = phase ? 0 : 512;
        const int nkt  = phase ? 2 : 8;            // 256-key tiles
        const int kt0  = (!phase && qt < 8) ? 2 : 0;
        const float extra = phase ? 1536.0f : 0.0f;

        const unsigned short* Kg = k_ws + (h * TOTAL + base) * 64;
        const unsigned short* Vg = vt_ws + h * 64 * TOTAL + base;

        const unsigned short* Qrow = q_ws + ((h * TOTAL) + base + qt * 64 + 16 * w + c) * 64;
        const bf16x8 qa0 = *(const bf16x8*)(Qrow + 8 * g);
        const bf16x8 qa1 = *(const bf16x8*)(Qrow + 8 * g + 32);

        float m_old = NEG_BIG, l_old = 0.f;        // stats for q = 16w + c
        f32x4 o_acc[4];
#pragma unroll
        for (int n = 0; n < 4; ++n) o_acc[n] = (f32x4){0.f, 0.f, 0.f, 0.f};

        auto STAGE_K = [&](int kt) {
#pragma unroll
            for (int i = 0; i < 8; ++i) {
                const int off = w * 8192 + i * 1024;
                const int ba  = off + lane * 16;
                const int row = ba >> 7;
                const int slot = (ba & 127) >> 4;
                gload16(Kg + (kt * 256 + row) * 64 + ((slot ^ (row & 7)) * 8),
                        (char*)&Kbuf[0] + off);
            }
        };
        auto STAGE_V = [&](int kt, int vb) {
#pragma unroll
            for (int i = 0; i < 8; ++i) {
                const int off = w * 8192 + i * 1024;
                const int ba  = off + lane * 16;
                const int dd  = ba >> 9;
                const int slot = (ba & 511) >> 4;
                gload16(Vg + dd * TOTAL + kt * 256 + ((slot ^ (dd & 7)) * 8),
                        (char*)&Vbuf[vb][0] + off);
            }
        };

        if (phase) __syncthreads();
        STAGE_K(kt0);
        STAGE_V(kt0, cur);

        for (int kt = kt0; kt < nkt; ++kt) {
            __syncthreads();           // A: drains vmcnt -> K(kt), V[cur] ready

            f32x4 s_acc[16];
#pragma unroll
            for (int n = 0; n < 16; ++n) {
                const int row = 16 * n + c;
                const bf16x8 kb0 = *(const bf16x8*)&Kbuf[row * 64 + ((g + 0) ^ c7) * 8];
                const bf16x8 kb1 = *(const bf16x8*)&Kbuf[row * 64 + ((g + 4) ^ c7) * 8];
                f32x4 a = __builtin_amdgcn_mfma_f32_16x16x32_bf16(kb0, qa0, (f32x4){0.f,0.f,0.f,0.f}, 0, 0, 0);
                s_acc[n] = __builtin_amdgcn_mfma_f32_16x16x32_bf16(kb1, qa1, a, 0, 0, 0);
            }
            __syncthreads();           // B: QK's LDS reads retired -> K buffer free
            if (kt + 1 < nkt) STAGE_K(kt + 1);

            // softmax (exp2-domain) with defer-max (T13, THR=8)
            f32x4 m4 = s_acc[0];
#pragma unroll
            for (int n = 1; n < 16; ++n)
#pragma unroll
                for (int r = 0; r < 4; ++r) m4[r] = fmaxf(m4[r], s_acc[n][r]);
            float tm = fmaxf(fmaxf(m4[0], m4[1]), fmaxf(m4[2], m4[3])) * LOG2E_8;
            tm = fmaxf(tm, __shfl_xor(tm, 16));
            tm = fmaxf(tm, __shfl_xor(tm, 32));
            if (!__all(tm <= m_old + 8.0f)) {
                const float m_new = fmaxf(m_old, tm);
                const float corr = exp2f(m_old - m_new);
                float corr_r[4];
#pragma unroll
                for (int r = 0; r < 4; ++r) corr_r[r] = __shfl(corr, 4 * g + r);
#pragma unroll
                for (int n = 0; n < 4; ++n)
#pragma unroll
                    for (int r = 0; r < 4; ++r) o_acc[n][r] *= corr_r[r];
                l_old *= corr;
                m_old = m_new;
            }
            float rs = 0.f;
#pragma unroll
            for (int n = 0; n < 16; ++n)
#pragma unroll
                for (int r = 0; r < 4; ++r) {
                    const float pv = exp2f(fmaf(s_acc[n][r], LOG2E_8, -m_old));
                    s_acc[n][r] = pv;
                    rs += pv;
                }
            rs += __shfl_xor(rs, 16);
            rs += __shfl_xor(rs, 32);
            l_old += rs;

#pragma unroll
            for (int n = 0; n < 16; ++n) {
                ushort4v pk;
#pragma unroll
                for (int r = 0; r < 4; ++r) pk[r] = f2bf(s_acc[n][r]);
                *(ushort4v*)&P_lds[16 * w + c][16 * n + 4 * g] = pk;
            }

            if (kt + 1 < nkt) STAGE_V(kt + 1, cur ^ 1);   // overlap with PV below

#pragma unroll
            for (int kk = 0; kk < 8; ++kk) {
                const bf16x8 pa = *(const bf16x8*)&P_lds[16 * w + c][8 * g + 32 * kk];
                const int vslot = (g + 4 * kk) ^ c7;
#pragma unroll
                for (int n = 0; n < 4; ++n) {
                    const bf16x8 vb = *(const bf16x8*)&Vbuf[cur][(16 * n + c) * 256 + vslot * 8];
                    o_acc[n] = __builtin_amdgcn_mfma_f32_16x16x32_bf16(pa, vb, o_acc[n], 0, 0, 0);
                }
            }
            cur ^= 1;
        }

        float inv_own;
        if (extra > 0.f) {
            const float mn  = fmaxf(m_old, 0.f);
            const float ccf = exp2f(m_old - mn);
            const float l   = l_old * ccf + extra * exp2f(-mn);
            inv_own = ccf / l;
        } else {
            inv_own = 1.0f / l_old;
        }
        float inv_r[4];
#pragma unroll
        for (int r = 0; r < 4; ++r) inv_r[r] = __shfl(inv_own, 4 * g + r);
        unsigned short* yb = y + (base + qt * 64 + 16 * w) * 512 + h * 64;
#pragma unroll
        for (int n = 0; n < 4; ++n)
#pragma unroll
            for (int r = 0; r < 4; ++r)
                yb[(4 * g + r) * 512 + 16 * n + c] = f2bf(o_acc[n][r] * inv_r[r]);
    }
}

// ---------------- output projection: bf16 MFMA, 64x64 tile (proven) -----------
__global__ __launch_bounds__(256) void proj_mfma_kernel(
    const unsigned short* __restrict__ A,    // y_bf [2560][512]
    const unsigned short* __restrict__ Bm,   // projw_bf [512][512]
    const float* __restrict__ bias,
    float* __restrict__ out)
{
    __shared__ unsigned short Abuf[2][64 * 64];
    __shared__ unsigned short Bbuf[2][64 * 64];
    const int m0 = blockIdx.x * 64;
    const int n0 = blockIdx.y * 64;
    const int t = threadIdx.x;
    const int w = t >> 6, lane = t & 63;
    const int wr = w >> 1, wc = w & 1;
    const int c = lane & 15, g = lane >> 4;

    auto STAGE = [&](int kt, int cur) {
#pragma unroll
        for (int i = 0; i < 2; ++i) {
            const int off = w * 2048 + i * 1024;
            const int ba  = off + lane * 16;
            const int row = ba >> 7;
            const int slot = (ba & 127) >> 4;
            gload16(A  + (m0 + row) * 512 + kt * 64 + ((slot ^ (row & 7)) * 8),
                    (char*)&Abuf[cur][0] + off);
            gload16(Bm + (n0 + row) * 512 + kt * 64 + ((slot ^ (row & 7)) * 8),
                    (char*)&Bbuf[cur][0] + off);
        }
    };

    f32x4 acc[2][2];
#pragma unroll
    for (int mi = 0; mi < 2; ++mi)
#pragma unroll
        for (int ni = 0; ni < 2; ++ni) acc[mi][ni] = (f32x4){0.f, 0.f, 0.f, 0.f};

    STAGE(0, 0);
    int cur = 0;
    for (int kt = 0; kt < 8; ++kt) {
        __syncthreads();
        if (kt + 1 < 8) STAGE(kt + 1, cur ^ 1);
#pragma unroll
        for (int kk = 0; kk < 2; ++kk) {
            bf16x8 af[2], bfr[2];
#pragma unroll
            for (int mi = 0; mi < 2; ++mi) {
                const int row = wr * 32 + mi * 16 + c;
                af[mi] = *(const bf16x8*)&Abuf[cur][row * 64 + ((g + 4 * kk) ^ (row & 7)) * 8];
            }
#pragma unroll
            for (int ni = 0; ni < 2; ++ni) {
                const int row = wc * 32 + ni * 16 + c;
                bfr[ni] = *(const bf16x8*)&Bbuf[cur][row * 64 + ((g + 4 * kk) ^ (row & 7)) * 8];
            }
#pragma unroll
            for (int mi = 0; mi < 2; ++mi)
#pragma unroll
                for (int ni = 0; ni < 2; ++ni)
                    acc[mi][ni] = __builtin_amdgcn_mfma_f32_16x16x32_bf16(af[mi], bfr[ni], acc[mi][ni], 0, 0, 0);
        }
        cur ^= 1;
    }

#pragma unroll
    for (int mi = 0; mi < 2; ++mi)
#pragma unroll
        for (int ni = 0; ni < 2; ++ni) {
            const int col = n0 + wc * 32 + ni * 16 + c;
            const float bv = bias[col];
#pragma unroll
            for (int r = 0; r < 4; ++r) {
                const int p = m0 + wr * 32 + mi * 16 + 4 * g + r;
                out[p * 512 + col] = acc[mi][ni][r] + bv;
            }
        }
}

extern "C" void kernel_launch(void* const* d_in, const int* in_sizes, int n_in,
                              void* d_out, int out_size, void* d_ws, size_t ws_size,
                              hipStream_t stream) {
    const float* features = (const float*)d_in[0];
    const float* coords   = (const float*)d_in[1];
    const float* qkv_w    = (const float*)d_in[2];
    const float* proj_w   = (const float*)d_in[3];
    const float* proj_b   = (const float*)d_in[4];
    const float* pos_w    = (const float*)d_in[5];
    const float* pos_b    = (const float*)d_in[6];
    float* out = (float*)d_out;

    float* pos_ws = (float*)d_ws;                                    // 163840 f32
    unsigned short* feat_bf  = (unsigned short*)(pos_ws + TOTAL * 64);
    unsigned short* qkvw_bf  = feat_bf + 2560 * 512;
    unsigned short* projw_bf = qkvw_bf + 1536 * 512;
    unsigned short* q_ws  = projw_bf + 512 * 512;
    unsigned short* k_ws  = q_ws  + 8 * TOTAL * 64;
    unsigned short* vt_ws = k_ws  + 8 * TOTAL * 64;
    unsigned short* y_bf  = vt_ws + 8 * TOTAL * 64;                  // 2560*512 bf16

    pos_cast_kernel<<<dim3(1792), dim3(256), 0, stream>>>(
        coords, pos_w, pos_b, features, qkv_w, proj_w,
        pos_ws, feat_bf, qkvw_bf, projw_bf);
    qkv_mfma_kernel<<<dim3(40, 24), dim3(256), 0, stream>>>(
        feat_bf, qkvw_bf, pos_ws, q_ws, k_ws, vt_ws);
    attn_kernel<<<dim3(256), dim3(256), 0, stream>>>(q_ws, k_ws, vt_ws, y_bf);
    proj_mfma_kernel<<<dim3(40, 8), dim3(256), 0, stream>>>(
        y_bf, projw_bf, proj_b, out);
}